// Round 4
// baseline (709.968 us; speedup 1.0000x reference)
//
#include <hip/hip_runtime.h>
#include <hip/hip_bf16.h>

#define DEV __device__ __forceinline__

// ---------- wave (64-lane) all-lanes butterflies ----------
DEV float waveAllMax(float x){
  #pragma unroll
  for(int o=1;o<64;o<<=1) x = fmaxf(x, __shfl_xor(x,o,64));
  return x;
}
DEV float waveAllSum(float x){
  #pragma unroll
  for(int o=1;o<64;o<<=1) x += __shfl_xor(x,o,64);
  return x;
}
DEV float waveReduceMax(float x){
  #pragma unroll
  for(int o=32;o>0;o>>=1) x = fmaxf(x, __shfl_down(x,o,64));
  return x;
}
DEV float waveReduceSum(float x){
  #pragma unroll
  for(int o=32;o>0;o>>=1) x += __shfl_down(x,o,64);
  return x;
}
// ---------- 256-thread block helpers (attn4_pre only) ----------
DEV float blockMax256(float x, float* sc){
  int lane = threadIdx.x & 63, wid = threadIdx.x >> 6;
  x = waveReduceMax(x);
  __syncthreads();
  if(lane==0) sc[wid] = x;
  __syncthreads();
  return fmaxf(fmaxf(sc[0],sc[1]), fmaxf(sc[2],sc[3]));
}
DEV float blockScan256(float x, float* sc, float& total){
  int lane = threadIdx.x & 63, wid = threadIdx.x >> 6;
  float v = x;
  #pragma unroll
  for(int o=1;o<64;o<<=1){ float t = __shfl_up(v,o,64); if(lane>=o) v += t; }
  __syncthreads();
  if(lane==63) sc[wid] = v;
  __syncthreads();
  float pre=0.f, tot=0.f;
  #pragma unroll
  for(int ww=0;ww<4;ww++){ float s = sc[ww]; tot += s; if(ww<wid) pre += s; }
  total = tot;
  return v + pre;
}
// fused (mean, var) over 128 threads (2 waves)
DEV void blockStats128(float x, float* sc, float& mean, float& var){
  float a = x, b = x*x;
  #pragma unroll
  for(int o=1;o<64;o<<=1){ a += __shfl_xor(a,o,64); b += __shfl_xor(b,o,64); }
  int lane = threadIdx.x & 63, wid = threadIdx.x >> 6;
  __syncthreads();
  if(lane==0){ sc[wid*2]=a; sc[wid*2+1]=b; }
  __syncthreads();
  float s1 = sc[0]+sc[2], s2 = sc[1]+sc[3];
  mean = s1 * 0.0078125f;
  var  = s2 * 0.0078125f - mean*mean;
}

// ---------- generic 128-wide linear body ----------
template<int R>
DEV void linear_body(const float* __restrict__ in, const float* __restrict__ W,
                     const float* __restrict__ bias, float* __restrict__ out,
                     int r0, int nrows, float sIn[R][128])
{
  int c = threadIdx.x;
  #pragma unroll
  for(int r=0;r<R;r++){
    int row = r0 + r;
    sIn[r][c] = (row < nrows) ? in[row*128 + c] : 0.f;
  }
  __syncthreads();
  float acc[R];
  float bv = bias[c];
  #pragma unroll
  for(int r=0;r<R;r++) acc[r] = bv;
  const float4* Wr = (const float4*)(W + c*128);
  #pragma unroll
  for(int k=0;k<32;k++){
    float4 w = Wr[k];
    #pragma unroll
    for(int r=0;r<R;r++){
      const float* s = &sIn[r][k*4];
      acc[r] += w.x*s[0] + w.y*s[1] + w.z*s[2] + w.w*s[3];
    }
  }
  #pragma unroll
  for(int r=0;r<R;r++){
    int row = r0 + r;
    if(row < nrows) out[row*128 + c] = acc[r];
  }
}

// one launch: qk1 (256 blk), v1 (256), k4 (256), q4 (4)
__global__ __launch_bounds__(128) void linear_fused(
  const float* __restrict__ in0, const float* __restrict__ W0, const float* __restrict__ b0, float* __restrict__ o0,
  const float* __restrict__ in1, const float* __restrict__ W1, const float* __restrict__ b1, float* __restrict__ o1,
  const float* __restrict__ in2, const float* __restrict__ W2, const float* __restrict__ b2, float* __restrict__ o2,
  const float* __restrict__ in3, const float* __restrict__ W3, const float* __restrict__ b3, float* __restrict__ o3)
{
  __shared__ float sIn[4][128];
  int bb = blockIdx.x;
  if(bb < 256)      linear_body<4>(in0, W0, b0, o0, bb*4,       1024, sIn);
  else if(bb < 512) linear_body<4>(in1, W1, b1, o1, (bb-256)*4, 1024, sIn);
  else if(bb < 768) linear_body<4>(in2, W2, b2, o2, (bb-512)*4, 1024, sIn);
  else              linear_body<4>(in3, W3, b3, o3, (bb-768)*4, 16,   sIn);
}

__global__ __launch_bounds__(128) void linear128(
  const float* __restrict__ in, const float* __restrict__ W, const float* __restrict__ bias,
  float* __restrict__ out, int nrows)
{
  __shared__ float sIn[4][128];
  linear_body<4>(in, W, bias, out, blockIdx.x*4, nrows, sIn);
}

// ---------- Layer-1 attention: wave-per-row ----------
// grid: 512 = 32 bh * 16 tiles; block 256 = 4 waves; wave w -> rows tile*16 + w*4 + r
__global__ __launch_bounds__(256) void attn1_kernel(
  const float* __restrict__ qk, const float* __restrict__ v1,
  const float* __restrict__ gamma, float* __restrict__ qs, float* __restrict__ aout)
{
  __shared__ float psW[4][256];
  int tile = blockIdx.x & 15;
  int bh   = blockIdx.x >> 4;
  int b = bh >> 3, h = bh & 7;
  int t = threadIdx.x, lane = t & 63, w = t >> 6;
  int d = lane & 15, jg = lane >> 4;
  int j0 = 4*lane;

  // K rows for this lane's 4 j (registers, reused across 4 rows)
  float4 kreg[4][4];
  #pragma unroll
  for(int u=0;u<4;u++){
    const float4* kr = (const float4*)(qk + (b*256 + j0 + u)*128 + h*16);
    kreg[u][0]=kr[0]; kreg[u][1]=kr[1]; kreg[u][2]=kr[2]; kreg[u][3]=kr[3];
  }
  // V panel in registers: lane (d,jg) holds v[jg*64+k][d]
  float vreg[64];
  const float* vbase = v1 + (b*256 + jg*64)*128 + h*16 + d;
  #pragma unroll
  for(int k=0;k<64;k++) vreg[k] = vbase[k*128];

  float ga = fabsf(gamma[h]);

  for(int r=0;r<4;r++){
    int i = tile*16 + w*4 + r;
    const float4* qr = (const float4*)(qk + (b*256 + i)*128 + h*16);
    float4 q0=qr[0], q1=qr[1], q2=qr[2], q3=qr[3];

    float raw[4]; float mloc = -3e38f;
    #pragma unroll
    for(int u=0;u<4;u++){
      const float4* kk = kreg[u];
      float s = q0.x*kk[0].x + q0.y*kk[0].y + q0.z*kk[0].z + q0.w*kk[0].w
              + q1.x*kk[1].x + q1.y*kk[1].y + q1.z*kk[1].z + q1.w*kk[1].w
              + q2.x*kk[2].x + q2.y*kk[2].y + q2.z*kk[2].z + q2.w*kk[2].w
              + q3.x*kk[3].x + q3.y*kk[3].y + q3.z*kk[3].z + q3.w*kk[3].w;
      raw[u] = s * 0.25f;
      if(j0+u <= i) mloc = fmaxf(mloc, raw[u]);
    }
    float m1 = waveAllMax(mloc);
    float e[4], c[4]; float lsum = 0.f;
    #pragma unroll
    for(int u=0;u<4;u++){
      e[u] = (j0+u <= i) ? __expf(raw[u]-m1) : 0.f;
      lsum += e[u]; c[u] = lsum;
    }
    // wave inclusive scan of per-lane sums
    float s = lsum;
    #pragma unroll
    for(int o=1;o<64;o<<=1){ float tv = __shfl_up(s,o,64); if(lane>=o) s += tv; }
    float pre = s - lsum;
    float tot = __shfl(s, 63, 64);
    float invtot = 1.f/tot;

    float s2v[4]; float m2loc = -3e38f;
    #pragma unroll
    for(int u=0;u<4;u++){
      int j = j0+u;
      float cum  = (pre + c[u]) * invtot;
      float remn = fmaxf(1.f - cum, 0.f);
      float dist = sqrtf(remn * fabsf((float)(j - i)));
      float eff  = fminf(fmaxf(__expf(-ga*dist), 1e-5f), 1e5f);
      s2v[u] = raw[u]*eff;
      if(j <= i) m2loc = fmaxf(m2loc, s2v[u]);
    }
    float m2 = waveAllMax(m2loc);
    float e2[4]; float zloc = 0.f;
    #pragma unroll
    for(int u=0;u<4;u++){
      e2[u] = (j0+u <= i) ? __expf(s2v[u]-m2) : 0.f;
      zloc += e2[u];
    }
    float Z = waveAllSum(zloc);
    float invZ = 1.f/Z;
    float p0=e2[0]*invZ, p1=e2[1]*invZ, p2=e2[2]*invZ, p3=e2[3]*invZ;

    *(float4*)(qs + ((size_t)(bh*256 + i))*256 + j0) = make_float4(p0,p1,p2,p3);

    __syncthreads();
    *(float4*)&psW[w][j0] = make_float4(p0,p1,p2,p3);
    __syncthreads();
    float acc = 0.f;
    const float4* pw = (const float4*)&psW[w][jg*64];
    #pragma unroll
    for(int k=0;k<16;k++){
      float4 pk = pw[k];
      acc += pk.x*vreg[4*k] + pk.y*vreg[4*k+1] + pk.z*vreg[4*k+2] + pk.w*vreg[4*k+3];
    }
    acc += __shfl_xor(acc,16,64);
    acc += __shfl_xor(acc,32,64);
    if(lane < 16)
      aout[(b*256 + i)*128 + h*16 + d] = acc;
  }
}

// proj(Wo) + residual + LayerNorm -> p (fp32)
template<int R>
__global__ __launch_bounds__(128) void projresln_p(
  const float* __restrict__ cin, const float* __restrict__ Wo, const float* __restrict__ bo,
  const float* __restrict__ resid, const float* __restrict__ lng, const float* __restrict__ lnb,
  float* __restrict__ outp)
{
  __shared__ float sIn[R][128];
  __shared__ float sc[4];
  int r0 = blockIdx.x * R;
  int c = threadIdx.x;
  #pragma unroll
  for(int r=0;r<R;r++) sIn[r][c] = cin[(r0+r)*128 + c];
  __syncthreads();
  float x[R];
  float bv = bo[c];
  #pragma unroll
  for(int r=0;r<R;r++) x[r] = bv;
  const float4* Wr = (const float4*)(Wo + c*128);
  #pragma unroll
  for(int k=0;k<32;k++){
    float4 w = Wr[k];
    #pragma unroll
    for(int r=0;r<R;r++){
      const float* s = &sIn[r][k*4];
      x[r] += w.x*s[0] + w.y*s[1] + w.z*s[2] + w.w*s[3];
    }
  }
  #pragma unroll
  for(int r=0;r<R;r++) x[r] += resid[(r0+r)*128 + c];
  float g = lng[c], bb = lnb[c];
  for(int r=0;r<R;r++){
    float m, var;
    blockStats128(x[r], sc, m, var);
    outp[(r0+r)*128 + c] = (x[r]-m) * rsqrtf(var + 1e-5f) * g + bb;
  }
}

// proj(Wo) + residual(know) + LN -> z (fp32, layout (b, i, n, c))
template<int R>
__global__ __launch_bounds__(128) void projresln_z(
  const float* __restrict__ cin, const float* __restrict__ Wo, const float* __restrict__ bo,
  const float* __restrict__ know, const float* __restrict__ lng, const float* __restrict__ lnb,
  float* __restrict__ zout)
{
  __shared__ float sIn[R][128];
  __shared__ float sc[4];
  int r0 = blockIdx.x * R;
  int c = threadIdx.x;
  #pragma unroll
  for(int r=0;r<R;r++) sIn[r][c] = cin[(r0+r)*128 + c];
  __syncthreads();
  float x[R];
  float bv = bo[c];
  #pragma unroll
  for(int r=0;r<R;r++) x[r] = bv;
  const float4* Wr = (const float4*)(Wo + c*128);
  #pragma unroll
  for(int k=0;k<32;k++){
    float4 w = Wr[k];
    #pragma unroll
    for(int r=0;r<R;r++){
      const float* s = &sIn[r][k*4];
      x[r] += w.x*s[0] + w.y*s[1] + w.z*s[2] + w.w*s[3];
    }
  }
  float g = lng[c], bb = lnb[c];
  for(int r=0;r<R;r++){
    int row = r0 + r;                 // row = (b*16+n)*256 + i
    int n = (row >> 8) & 15;
    x[r] += know[n*128 + c];
    float m, var;
    blockStats128(x[r], sc, m, var);
    float y = (x[r]-m) * rsqrtf(var + 1e-5f) * g + bb;
    int b = row >> 12, i = row & 255;
    zout[(((size_t)(b*256 + i))*16 + n)*128 + c] = y;
  }
}

DEV float dot16(const float* a, const float* b){
  float s = 0.f;
  #pragma unroll
  for(int k=0;k<16;k++) s += a[k]*b[k];
  return s;
}

// Layer-4 precompute: raw[j] (i-independent) and prefix P[j] of exp(raw - M)
__global__ __launch_bounds__(256) void attn4_pre(
  const float* __restrict__ q4, const float* __restrict__ k4,
  float* __restrict__ raw4, float* __restrict__ P4)
{
  __shared__ float sc4[4];
  int bnh = blockIdx.x;                 // b*128 + n*8 + h
  int b = bnh >> 7, n = (bnh >> 3) & 15, h = bnh & 7;
  int j = threadIdx.x;
  const float* qrow = q4 + n*128 + h*16;
  const float* krow = k4 + (b*256 + j)*128 + h*16;
  float raw = dot16(qrow, krow) * 0.25f;
  float M = blockMax256(raw, sc4);
  float E = __expf(raw - M);
  float tot;
  float P = blockScan256(E, sc4, tot);
  raw4[bnh*256 + j] = raw;
  P4[bnh*256 + j]   = P;
}

// ---------- Layer-4 main: wave-per-row ----------
// grid: 1024 = 512 bnh * 2 halves; block 256 = 4 waves; wave w -> rows half*128 + w*32 + r
__global__ __launch_bounds__(256) void attn4_main(
  const float* __restrict__ raw4, const float* __restrict__ P4,
  const float* __restrict__ v4, const float* __restrict__ gamma,
  float* __restrict__ ks, float* __restrict__ aout)
{
  __shared__ float psW[4][256];
  int half = blockIdx.x & 1;
  int bnh  = blockIdx.x >> 1;
  int b = bnh >> 7, n = (bnh >> 3) & 15, h = bnh & 7;
  int t = threadIdx.x, lane = t & 63, w = t >> 6;
  int d = lane & 15, jg = lane >> 4;
  int j0 = 4*lane;

  // per-wave register copies of raw & prefix P (i-independent)
  float4 rw = *(const float4*)(raw4 + bnh*256 + j0);
  float4 Pv = *(const float4*)(P4   + bnh*256 + j0);
  const float* Pbase = P4 + bnh*256;

  // V panel in registers
  float vreg[64];
  const float* vbase = v4 + (b*256 + jg*64)*128 + h*16 + d;
  #pragma unroll
  for(int k=0;k<64;k++) vreg[k] = vbase[k*128];

  float g4a = fabsf(gamma[h]);
  size_t ksrowbase = ((size_t)(b*8 + h)*256)*4096 + (size_t)n*256 + j0;
  float P_[4] = {Pv.x, Pv.y, Pv.z, Pv.w};
  float R_[4] = {rw.x, rw.y, rw.z, rw.w};

  for(int r=0;r<32;r++){
    int i = half*128 + w*32 + r;     // wave-uniform
    float p0=0.f,p1=0.f,p2=0.f,p3=0.f;
    if(i > 0){
      float invPm1 = 1.f / Pbase[i-1];
      float s2v[4]; float mloc = -3e38f;
      #pragma unroll
      for(int u=0;u<4;u++){
        int j = j0+u;
        float cum  = P_[u]*invPm1;            // valid only for j<i; masked below
        float remn = fmaxf(1.f - cum, 0.f);
        float dist = sqrtf(remn * fabsf((float)(j - i)));
        float eff  = fminf(fmaxf(__expf(-g4a*dist), 1e-5f), 1e5f);
        float s2   = R_[u]*eff;
        s2v[u] = s2;
        if(j < i) mloc = fmaxf(mloc, s2);
      }
      float m2 = waveAllMax(mloc);
      float e_[4]; float zloc = 0.f;
      #pragma unroll
      for(int u=0;u<4;u++){
        float e = (j0+u < i) ? __expf(s2v[u]-m2) : 0.f;
        e_[u] = e; zloc += e;
      }
      float Z = waveAllSum(zloc);
      float sc = fminf(Z, 5.f)/Z;              // maxout: max(p)=1/Z
      p0=e_[0]*sc; p1=e_[1]*sc; p2=e_[2]*sc; p3=e_[3]*sc;
    }
    *(float4*)(ks + ksrowbase + (size_t)i*4096) = make_float4(p0,p1,p2,p3);

    __syncthreads();
    *(float4*)&psW[w][j0] = make_float4(p0,p1,p2,p3);
    __syncthreads();
    float acc = 0.f;
    const float4* pw = (const float4*)&psW[w][jg*64];
    #pragma unroll
    for(int k=0;k<16;k++){
      float4 pk = pw[k];
      acc += pk.x*vreg[4*k] + pk.y*vreg[4*k+1] + pk.z*vreg[4*k+2] + pk.w*vreg[4*k+3];
    }
    acc += __shfl_xor(acc,16,64);
    acc += __shfl_xor(acc,32,64);
    if(lane < 16)
      aout[((b*16+n)*256 + i)*128 + h*16 + d] = acc;
  }
}

extern "C" void kernel_launch(void* const* d_in, const int* in_sizes, int n_in,
                              void* d_out, int out_size, void* d_ws, size_t ws_size,
                              hipStream_t stream)
{
  (void)in_sizes; (void)n_in; (void)out_size; (void)ws_size;
  const float* q_emb   = (const float*)d_in[0];
  const float* s_emb   = (const float*)d_in[1];
  const float* b1_Wq   = (const float*)d_in[3];
  const float* b1_bq   = (const float*)d_in[4];
  const float* b1_Wv   = (const float*)d_in[5];
  const float* b1_bv   = (const float*)d_in[6];
  const float* b1_Wo   = (const float*)d_in[7];
  const float* b1_bo   = (const float*)d_in[8];
  const float* b1_gamma= (const float*)d_in[9];
  const float* b1_lng  = (const float*)d_in[10];
  const float* b1_lnb  = (const float*)d_in[11];
  const float* b4_Wq   = (const float*)d_in[12];
  const float* b4_bq   = (const float*)d_in[13];
  const float* b4_Wk   = (const float*)d_in[14];
  const float* b4_bk   = (const float*)d_in[15];
  const float* b4_Wv   = (const float*)d_in[16];
  const float* b4_bv   = (const float*)d_in[17];
  const float* b4_Wo   = (const float*)d_in[18];
  const float* b4_bo   = (const float*)d_in[19];
  const float* b4_gamma= (const float*)d_in[20];
  const float* b4_lng  = (const float*)d_in[21];
  const float* b4_lnb  = (const float*)d_in[22];
  const float* know    = (const float*)d_in[23];

  float* w    = (float*)d_ws;
  float* qk1  = w;                 // 131072
  float* v1   = w + 131072;        // 131072
  float* a1o  = w + 262144;        // 131072
  float* p    = w + 393216;        // 131072
  float* q4   = w + 524288;        // 2048
  float* k4   = w + 526336;        // 131072
  float* v4   = w + 657408;        // 131072
  float* raw4 = w + 788480;        // 131072
  float* P4   = w + 919552;        // 131072
  float* a4o  = w + 1050624;       // 2097152

  float* z_out  = (float*)d_out;                 // (4,256,2048)
  float* qs_out = z_out + 2097152;               // (4,8,256,256)
  float* ks_out = z_out + 4194304;               // (4,8,256,16,256)

  // fused projections: qk1, v1, k4, q4
  linear_fused<<<772,128,0,stream>>>(
      q_emb, b1_Wq, b1_bq, qk1,
      s_emb, b1_Wv, b1_bv, v1,
      q_emb, b4_Wk, b4_bk, k4,
      know,  b4_Wq, b4_bq, q4);

  attn1_kernel<<<512,256,0,stream>>>(qk1, v1, b1_gamma, qs_out, a1o);
  projresln_p<8><<<128,128,0,stream>>>(a1o, b1_Wo, b1_bo, q_emb, b1_lng, b1_lnb, p);

  linear128<<<256,128,0,stream>>>(p, b4_Wv, b4_bv, v4, 1024);

  attn4_pre<<<512,256,0,stream>>>(q4, k4, raw4, P4);
  attn4_main<<<1024,256,0,stream>>>(raw4, P4, v4, b4_gamma, ks_out, a4o);

  projresln_z<8><<<2048,128,0,stream>>>(a4o, b4_Wo, b4_bo, know, b4_lng, b4_lnb, z_out);
}

// Round 5
// 319.208 us; speedup vs baseline: 2.2242x; 2.2242x over previous
//
#include <hip/hip_runtime.h>
#include <hip/hip_bf16.h>

#define DEV __device__ __forceinline__

DEV float4 f4fma(float4 a, float s, float4 w){
  a.x = fmaf(s, w.x, a.x); a.y = fmaf(s, w.y, a.y);
  a.z = fmaf(s, w.z, a.z); a.w = fmaf(s, w.w, a.w);
  return a;
}
DEV float4 f4add(float4 a, float4 b){
  a.x+=b.x; a.y+=b.y; a.z+=b.z; a.w+=b.w; return a;
}

// ---------- wave (64-lane) butterflies ----------
DEV float waveAllMax(float x){
  #pragma unroll
  for(int o=1;o<64;o<<=1) x = fmaxf(x, __shfl_xor(x,o,64));
  return x;
}
DEV float waveAllSum(float x){
  #pragma unroll
  for(int o=1;o<64;o<<=1) x += __shfl_xor(x,o,64);
  return x;
}
DEV float waveReduceMax(float x){
  #pragma unroll
  for(int o=32;o>0;o>>=1) x = fmaxf(x, __shfl_down(x,o,64));
  return x;
}
// ---------- 256-thread block helpers (attn4_pre only) ----------
DEV float blockMax256(float x, float* sc){
  int lane = threadIdx.x & 63, wid = threadIdx.x >> 6;
  x = waveReduceMax(x);
  __syncthreads();
  if(lane==0) sc[wid] = x;
  __syncthreads();
  return fmaxf(fmaxf(sc[0],sc[1]), fmaxf(sc[2],sc[3]));
}
DEV float blockScan256(float x, float* sc, float& total){
  int lane = threadIdx.x & 63, wid = threadIdx.x >> 6;
  float v = x;
  #pragma unroll
  for(int o=1;o<64;o<<=1){ float t = __shfl_up(v,o,64); if(lane>=o) v += t; }
  __syncthreads();
  if(lane==63) sc[wid] = v;
  __syncthreads();
  float pre=0.f, tot=0.f;
  #pragma unroll
  for(int ww=0;ww<4;ww++){ float s = sc[ww]; tot += s; if(ww<wid) pre += s; }
  total = tot;
  return v + pre;
}

// ================= GEMM16: out(16x128) = in @ W^T + b, epilogue variants ====
// EPI 0: plain store. EPI 1: +aux[row] residual, LN, store row-major.
// EPI 2: +aux[n] (know), LN, scatter to z layout (b,i,n,c).
// Block 256 thr. Thread (og=t&31, rg=t>>5): cols og*4..+3, rows rg*2..+1.
// W staged transposed in LDS in two 64-col chunks, pad 132 (b128-aligned,
// conflict-free on compute reads).
template<int EPI>
DEV void gemm16_body(const float* __restrict__ in, const float* __restrict__ W,
                     const float* __restrict__ bias, const float* __restrict__ aux,
                     const float* __restrict__ lng, const float* __restrict__ lnb,
                     float* __restrict__ out, int r0, int nrows,
                     float* sWT, float (*sIn)[128])
{
  const int t = threadIdx.x;
  for(int idx=t; idx<2048; idx+=256){
    int r = idx>>7, c = idx&127;
    int row = r0+r;
    sIn[r][c] = (row<nrows) ? in[(size_t)row*128+c] : 0.f;
  }
  const int og = t & 31, rg = t >> 5;
  const int o0 = og*4;
  const float* s0p = sIn[rg*2];
  const float* s1p = sIn[rg*2+1];
  float4 a0 = make_float4(0,0,0,0), a1 = make_float4(0,0,0,0);

  #pragma unroll
  for(int half=0; half<2; half++){
    int c0 = half*64;
    __syncthreads();                       // cover sIn stage / prev chunk reads
    for(int idx=t; idx<8192; idx+=256){    // stage W[:, c0:c0+64] transposed
      int o = idx>>6, cc = idx&63;
      sWT[cc*132 + o] = W[o*128 + c0 + cc];
    }
    __syncthreads();
    #pragma unroll 4
    for(int c=0;c<64;c+=4){
      float4 sA = *(const float4*)(s0p + c0 + c);
      float4 sB = *(const float4*)(s1p + c0 + c);
      const float* wp = sWT + c*132 + o0;
      float4 w0 = *(const float4*)(wp);
      float4 w1 = *(const float4*)(wp + 132);
      float4 w2 = *(const float4*)(wp + 264);
      float4 w3 = *(const float4*)(wp + 396);
      a0 = f4fma(a0, sA.x, w0); a0 = f4fma(a0, sA.y, w1);
      a0 = f4fma(a0, sA.z, w2); a0 = f4fma(a0, sA.w, w3);
      a1 = f4fma(a1, sB.x, w0); a1 = f4fma(a1, sB.y, w1);
      a1 = f4fma(a1, sB.z, w2); a1 = f4fma(a1, sB.w, w3);
    }
  }
  float4 bv = *(const float4*)(bias + o0);
  a0 = f4add(a0, bv); a1 = f4add(a1, bv);
  int row0 = r0 + rg*2, row1 = row0 + 1;

  if(EPI == 0){
    if(row0 < nrows) *(float4*)(out + (size_t)row0*128 + o0) = a0;
    if(row1 < nrows) *(float4*)(out + (size_t)row1*128 + o0) = a1;
  } else {
    const float *x0, *x1;
    if(EPI == 1){
      x0 = aux + (size_t)row0*128; x1 = aux + (size_t)row1*128;
    } else {
      x0 = aux + ((row0>>8)&15)*128; x1 = aux + ((row1>>8)&15)*128;
    }
    a0 = f4add(a0, *(const float4*)(x0 + o0));
    a1 = f4add(a1, *(const float4*)(x1 + o0));
    float s0 = a0.x+a0.y+a0.z+a0.w, s1 = a1.x+a1.y+a1.z+a1.w;
    float q0 = a0.x*a0.x+a0.y*a0.y+a0.z*a0.z+a0.w*a0.w;
    float q1 = a1.x*a1.x+a1.y*a1.y+a1.z*a1.z+a1.w*a1.w;
    #pragma unroll
    for(int o=1;o<32;o<<=1){
      s0 += __shfl_xor(s0,o,64); q0 += __shfl_xor(q0,o,64);
      s1 += __shfl_xor(s1,o,64); q1 += __shfl_xor(q1,o,64);
    }
    float m0 = s0*0.0078125f, v0 = q0*0.0078125f - m0*m0;
    float m1 = s1*0.0078125f, v1 = q1*0.0078125f - m1*m1;
    float i0 = rsqrtf(v0+1e-5f), i1 = rsqrtf(v1+1e-5f);
    float4 g  = *(const float4*)(lng + o0);
    float4 b2 = *(const float4*)(lnb + o0);
    float4 y0, y1;
    y0.x=(a0.x-m0)*i0*g.x+b2.x; y0.y=(a0.y-m0)*i0*g.y+b2.y;
    y0.z=(a0.z-m0)*i0*g.z+b2.z; y0.w=(a0.w-m0)*i0*g.w+b2.w;
    y1.x=(a1.x-m1)*i1*g.x+b2.x; y1.y=(a1.y-m1)*i1*g.y+b2.y;
    y1.z=(a1.z-m1)*i1*g.z+b2.z; y1.w=(a1.w-m1)*i1*g.w+b2.w;
    float *p0, *p1;
    if(EPI == 1){
      p0 = out + (size_t)row0*128; p1 = out + (size_t)row1*128;
    } else {
      int n0=(row0>>8)&15, b0=row0>>12, i0i=row0&255;
      int n1=(row1>>8)&15, b1=row1>>12, i1i=row1&255;
      p0 = out + ((((size_t)b0*256+i0i)*16+n0)<<7);
      p1 = out + ((((size_t)b1*256+i1i)*16+n1)<<7);
    }
    *(float4*)(p0 + o0) = y0;
    *(float4*)(p1 + o0) = y1;
  }
}

template<int EPI>
__global__ __launch_bounds__(256) void gemm16_kernel(
  const float* __restrict__ in, const float* __restrict__ W,
  const float* __restrict__ bias, const float* __restrict__ aux,
  const float* __restrict__ lng, const float* __restrict__ lnb,
  float* __restrict__ out, int nrows)
{
  __shared__ float sWT[64*132];
  __shared__ float sIn[16][128];
  gemm16_body<EPI>(in, W, bias, aux, lng, lnb, out, blockIdx.x*16, nrows, sWT, sIn);
}

// one launch for the 4 independent projections: qk1(64), v1(64), k4(64), q4(1)
__global__ __launch_bounds__(256) void proj4_kernel(
  const float* __restrict__ in0, const float* __restrict__ W0, const float* __restrict__ b0, float* __restrict__ o0,
  const float* __restrict__ in1, const float* __restrict__ W1, const float* __restrict__ b1, float* __restrict__ o1,
  const float* __restrict__ in2, const float* __restrict__ W2, const float* __restrict__ b2, float* __restrict__ o2,
  const float* __restrict__ in3, const float* __restrict__ W3, const float* __restrict__ b3, float* __restrict__ o3)
{
  __shared__ float sWT[64*132];
  __shared__ float sIn[16][128];
  int bb = blockIdx.x;
  if(bb < 64)       gemm16_body<0>(in0,W0,b0,nullptr,nullptr,nullptr,o0, bb*16,      1024, sWT,sIn);
  else if(bb < 128) gemm16_body<0>(in1,W1,b1,nullptr,nullptr,nullptr,o1,(bb-64)*16,  1024, sWT,sIn);
  else if(bb < 192) gemm16_body<0>(in2,W2,b2,nullptr,nullptr,nullptr,o2,(bb-128)*16, 1024, sWT,sIn);
  else              gemm16_body<0>(in3,W3,b3,nullptr,nullptr,nullptr,o3, 0,          16,   sWT,sIn);
}

// ---------- Layer-1 attention: wave-per-row (unchanged from R4) ----------
__global__ __launch_bounds__(256) void attn1_kernel(
  const float* __restrict__ qk, const float* __restrict__ v1,
  const float* __restrict__ gamma, float* __restrict__ qs, float* __restrict__ aout)
{
  __shared__ float psW[4][256];
  int tile = blockIdx.x & 15;
  int bh   = blockIdx.x >> 4;
  int b = bh >> 3, h = bh & 7;
  int t = threadIdx.x, lane = t & 63, w = t >> 6;
  int d = lane & 15, jg = lane >> 4;
  int j0 = 4*lane;

  float4 kreg[4][4];
  #pragma unroll
  for(int u=0;u<4;u++){
    const float4* kr = (const float4*)(qk + (b*256 + j0 + u)*128 + h*16);
    kreg[u][0]=kr[0]; kreg[u][1]=kr[1]; kreg[u][2]=kr[2]; kreg[u][3]=kr[3];
  }
  float vreg[64];
  const float* vbase = v1 + (b*256 + jg*64)*128 + h*16 + d;
  #pragma unroll
  for(int k=0;k<64;k++) vreg[k] = vbase[k*128];

  float ga = fabsf(gamma[h]);

  for(int r=0;r<4;r++){
    int i = tile*16 + w*4 + r;
    const float4* qr = (const float4*)(qk + (b*256 + i)*128 + h*16);
    float4 q0=qr[0], q1=qr[1], q2=qr[2], q3=qr[3];

    float raw[4]; float mloc = -3e38f;
    #pragma unroll
    for(int u=0;u<4;u++){
      const float4* kk = kreg[u];
      float s = q0.x*kk[0].x + q0.y*kk[0].y + q0.z*kk[0].z + q0.w*kk[0].w
              + q1.x*kk[1].x + q1.y*kk[1].y + q1.z*kk[1].z + q1.w*kk[1].w
              + q2.x*kk[2].x + q2.y*kk[2].y + q2.z*kk[2].z + q2.w*kk[2].w
              + q3.x*kk[3].x + q3.y*kk[3].y + q3.z*kk[3].z + q3.w*kk[3].w;
      raw[u] = s * 0.25f;
      if(j0+u <= i) mloc = fmaxf(mloc, raw[u]);
    }
    float m1 = waveAllMax(mloc);
    float e[4], c[4]; float lsum = 0.f;
    #pragma unroll
    for(int u=0;u<4;u++){
      e[u] = (j0+u <= i) ? __expf(raw[u]-m1) : 0.f;
      lsum += e[u]; c[u] = lsum;
    }
    float s = lsum;
    #pragma unroll
    for(int o=1;o<64;o<<=1){ float tv = __shfl_up(s,o,64); if(lane>=o) s += tv; }
    float pre = s - lsum;
    float tot = __shfl(s, 63, 64);
    float invtot = 1.f/tot;

    float s2v[4]; float m2loc = -3e38f;
    #pragma unroll
    for(int u=0;u<4;u++){
      int j = j0+u;
      float cum  = (pre + c[u]) * invtot;
      float remn = fmaxf(1.f - cum, 0.f);
      float dist = sqrtf(remn * fabsf((float)(j - i)));
      float eff  = fminf(fmaxf(__expf(-ga*dist), 1e-5f), 1e5f);
      s2v[u] = raw[u]*eff;
      if(j <= i) m2loc = fmaxf(m2loc, s2v[u]);
    }
    float m2 = waveAllMax(m2loc);
    float e2[4]; float zloc = 0.f;
    #pragma unroll
    for(int u=0;u<4;u++){
      e2[u] = (j0+u <= i) ? __expf(s2v[u]-m2) : 0.f;
      zloc += e2[u];
    }
    float Z = waveAllSum(zloc);
    float invZ = 1.f/Z;
    float p0=e2[0]*invZ, p1=e2[1]*invZ, p2=e2[2]*invZ, p3=e2[3]*invZ;

    *(float4*)(qs + ((size_t)(bh*256 + i))*256 + j0) = make_float4(p0,p1,p2,p3);

    __syncthreads();
    *(float4*)&psW[w][j0] = make_float4(p0,p1,p2,p3);
    __syncthreads();
    float acc = 0.f;
    const float4* pw = (const float4*)&psW[w][jg*64];
    #pragma unroll
    for(int k=0;k<16;k++){
      float4 pk = pw[k];
      acc += pk.x*vreg[4*k] + pk.y*vreg[4*k+1] + pk.z*vreg[4*k+2] + pk.w*vreg[4*k+3];
    }
    acc += __shfl_xor(acc,16,64);
    acc += __shfl_xor(acc,32,64);
    if(lane < 16)
      aout[(b*256 + i)*128 + h*16 + d] = acc;
  }
}

DEV float dot16(const float* a, const float* b){
  float s = 0.f;
  #pragma unroll
  for(int k=0;k<16;k++) s += a[k]*b[k];
  return s;
}

// Layer-4 precompute: raw[j] (i-independent) and prefix P[j] of exp(raw - M)
__global__ __launch_bounds__(256) void attn4_pre(
  const float* __restrict__ q4, const float* __restrict__ k4,
  float* __restrict__ raw4, float* __restrict__ P4)
{
  __shared__ float sc4[4];
  int bnh = blockIdx.x;                 // b*128 + n*8 + h
  int b = bnh >> 7, n = (bnh >> 3) & 15, h = bnh & 7;
  int j = threadIdx.x;
  const float* qrow = q4 + n*128 + h*16;
  const float* krow = k4 + (b*256 + j)*128 + h*16;
  float raw = dot16(qrow, krow) * 0.25f;
  float M = blockMax256(raw, sc4);
  float E = __expf(raw - M);
  float tot;
  float P = blockScan256(E, sc4, tot);
  raw4[bnh*256 + j] = raw;
  P4[bnh*256 + j]   = P;
}

// ---------- Layer-4 main: wave-per-row (unchanged from R4) ----------
__global__ __launch_bounds__(256) void attn4_main(
  const float* __restrict__ raw4, const float* __restrict__ P4,
  const float* __restrict__ v4, const float* __restrict__ gamma,
  float* __restrict__ ks, float* __restrict__ aout)
{
  __shared__ float psW[4][256];
  int half = blockIdx.x & 1;
  int bnh  = blockIdx.x >> 1;
  int b = bnh >> 7, n = (bnh >> 3) & 15, h = bnh & 7;
  int t = threadIdx.x, lane = t & 63, w = t >> 6;
  int d = lane & 15, jg = lane >> 4;
  int j0 = 4*lane;

  float4 rw = *(const float4*)(raw4 + bnh*256 + j0);
  float4 Pv = *(const float4*)(P4   + bnh*256 + j0);
  const float* Pbase = P4 + bnh*256;

  float vreg[64];
  const float* vbase = v4 + (b*256 + jg*64)*128 + h*16 + d;
  #pragma unroll
  for(int k=0;k<64;k++) vreg[k] = vbase[k*128];

  float g4a = fabsf(gamma[h]);
  size_t ksrowbase = ((size_t)(b*8 + h)*256)*4096 + (size_t)n*256 + j0;
  float P_[4] = {Pv.x, Pv.y, Pv.z, Pv.w};
  float R_[4] = {rw.x, rw.y, rw.z, rw.w};

  for(int r=0;r<32;r++){
    int i = half*128 + w*32 + r;
    float p0=0.f,p1=0.f,p2=0.f,p3=0.f;
    if(i > 0){
      float invPm1 = 1.f / Pbase[i-1];
      float s2v[4]; float mloc = -3e38f;
      #pragma unroll
      for(int u=0;u<4;u++){
        int j = j0+u;
        float cum  = P_[u]*invPm1;
        float remn = fmaxf(1.f - cum, 0.f);
        float dist = sqrtf(remn * fabsf((float)(j - i)));
        float eff  = fminf(fmaxf(__expf(-g4a*dist), 1e-5f), 1e5f);
        float s2   = R_[u]*eff;
        s2v[u] = s2;
        if(j < i) mloc = fmaxf(mloc, s2);
      }
      float m2 = waveAllMax(mloc);
      float e_[4]; float zloc = 0.f;
      #pragma unroll
      for(int u=0;u<4;u++){
        float e = (j0+u < i) ? __expf(s2v[u]-m2) : 0.f;
        e_[u] = e; zloc += e;
      }
      float Z = waveAllSum(zloc);
      float sc = fminf(Z, 5.f)/Z;
      p0=e_[0]*sc; p1=e_[1]*sc; p2=e_[2]*sc; p3=e_[3]*sc;
    }
    *(float4*)(ks + ksrowbase + (size_t)i*4096) = make_float4(p0,p1,p2,p3);

    __syncthreads();
    *(float4*)&psW[w][j0] = make_float4(p0,p1,p2,p3);
    __syncthreads();
    float acc = 0.f;
    const float4* pw = (const float4*)&psW[w][jg*64];
    #pragma unroll
    for(int k=0;k<16;k++){
      float4 pk = pw[k];
      acc += pk.x*vreg[4*k] + pk.y*vreg[4*k+1] + pk.z*vreg[4*k+2] + pk.w*vreg[4*k+3];
    }
    acc += __shfl_xor(acc,16,64);
    acc += __shfl_xor(acc,32,64);
    if(lane < 16)
      aout[((b*16+n)*256 + i)*128 + h*16 + d] = acc;
  }
}

extern "C" void kernel_launch(void* const* d_in, const int* in_sizes, int n_in,
                              void* d_out, int out_size, void* d_ws, size_t ws_size,
                              hipStream_t stream)
{
  (void)in_sizes; (void)n_in; (void)out_size; (void)ws_size;
  const float* q_emb   = (const float*)d_in[0];
  const float* s_emb   = (const float*)d_in[1];
  const float* b1_Wq   = (const float*)d_in[3];
  const float* b1_bq   = (const float*)d_in[4];
  const float* b1_Wv   = (const float*)d_in[5];
  const float* b1_bv   = (const float*)d_in[6];
  const float* b1_Wo   = (const float*)d_in[7];
  const float* b1_bo   = (const float*)d_in[8];
  const float* b1_gamma= (const float*)d_in[9];
  const float* b1_lng  = (const float*)d_in[10];
  const float* b1_lnb  = (const float*)d_in[11];
  const float* b4_Wq   = (const float*)d_in[12];
  const float* b4_bq   = (const float*)d_in[13];
  const float* b4_Wk   = (const float*)d_in[14];
  const float* b4_bk   = (const float*)d_in[15];
  const float* b4_Wv   = (const float*)d_in[16];
  const float* b4_bv   = (const float*)d_in[17];
  const float* b4_Wo   = (const float*)d_in[18];
  const float* b4_bo   = (const float*)d_in[19];
  const float* b4_gamma= (const float*)d_in[20];
  const float* b4_lng  = (const float*)d_in[21];
  const float* b4_lnb  = (const float*)d_in[22];
  const float* know    = (const float*)d_in[23];

  float* w    = (float*)d_ws;
  float* qk1  = w;                 // 131072
  float* v1   = w + 131072;        // 131072
  float* a1o  = w + 262144;        // 131072
  float* p    = w + 393216;        // 131072
  float* q4   = w + 524288;        // 2048
  float* k4   = w + 526336;        // 131072
  float* v4   = w + 657408;        // 131072
  float* raw4 = w + 788480;        // 131072
  float* P4   = w + 919552;        // 131072
  float* a4o  = w + 1050624;       // 2097152

  float* z_out  = (float*)d_out;                 // (4,256,2048)
  float* qs_out = z_out + 2097152;               // (4,8,256,256)
  float* ks_out = z_out + 4194304;               // (4,8,256,16,256)

  // fused projections: qk1, v1, k4, q4
  proj4_kernel<<<193,256,0,stream>>>(
      q_emb, b1_Wq, b1_bq, qk1,
      s_emb, b1_Wv, b1_bv, v1,
      q_emb, b4_Wk, b4_bk, k4,
      know,  b4_Wq, b4_bq, q4);

  attn1_kernel<<<512,256,0,stream>>>(qk1, v1, b1_gamma, qs_out, a1o);
  gemm16_kernel<1><<<64,256,0,stream>>>(a1o, b1_Wo, b1_bo, q_emb, b1_lng, b1_lnb, p, 1024);

  gemm16_kernel<0><<<64,256,0,stream>>>(p, b4_Wv, b4_bv, nullptr, nullptr, nullptr, v4, 1024);

  attn4_pre<<<512,256,0,stream>>>(q4, k4, raw4, P4);
  attn4_main<<<1024,256,0,stream>>>(raw4, P4, v4, b4_gamma, ks_out, a4o);

  gemm16_kernel<2><<<1024,256,0,stream>>>(a4o, b4_Wo, b4_bo, know, b4_lng, b4_lnb, z_out, 16384);
}

// Round 6
// 308.415 us; speedup vs baseline: 2.3020x; 1.0350x over previous
//
#include <hip/hip_runtime.h>
#include <hip/hip_bf16.h>

#define DEV __device__ __forceinline__

DEV float4 f4fma(float4 a, float s, float4 w){
  a.x = fmaf(s, w.x, a.x); a.y = fmaf(s, w.y, a.y);
  a.z = fmaf(s, w.z, a.z); a.w = fmaf(s, w.w, a.w);
  return a;
}
DEV float4 f4add(float4 a, float4 b){
  a.x+=b.x; a.y+=b.y; a.z+=b.z; a.w+=b.w; return a;
}

// ---------- wave (64-lane) butterflies ----------
DEV float waveAllMax(float x){
  #pragma unroll
  for(int o=1;o<64;o<<=1) x = fmaxf(x, __shfl_xor(x,o,64));
  return x;
}
DEV float waveAllSum(float x){
  #pragma unroll
  for(int o=1;o<64;o<<=1) x += __shfl_xor(x,o,64);
  return x;
}
DEV float waveReduceMax(float x){
  #pragma unroll
  for(int o=32;o>0;o>>=1) x = fmaxf(x, __shfl_down(x,o,64));
  return x;
}
// ---------- 256-thread block helpers ----------
DEV float blockMax256(float x, float* sc){
  int lane = threadIdx.x & 63, wid = threadIdx.x >> 6;
  x = waveReduceMax(x);
  __syncthreads();
  if(lane==0) sc[wid] = x;
  __syncthreads();
  return fmaxf(fmaxf(sc[0],sc[1]), fmaxf(sc[2],sc[3]));
}
DEV float blockScan256(float x, float* sc, float& total){
  int lane = threadIdx.x & 63, wid = threadIdx.x >> 6;
  float v = x;
  #pragma unroll
  for(int o=1;o<64;o<<=1){ float t = __shfl_up(v,o,64); if(lane>=o) v += t; }
  __syncthreads();
  if(lane==63) sc[wid] = v;
  __syncthreads();
  float pre=0.f, tot=0.f;
  #pragma unroll
  for(int ww=0;ww<4;ww++){ float s = sc[ww]; tot += s; if(ww<wid) pre += s; }
  total = tot;
  return v + pre;
}

// ================= GEMM16: out(16x128) = in @ W^T + b ======================
// EPI 0: plain store. EPI 2: +aux[n] (know), LN, scatter to z layout (b,i,n,c).
// Thread (og=t&31, rg=t>>5): cols og*4..+3, rows rg*2..+1.
template<int EPI>
DEV void gemm16_body(const float* __restrict__ in, const float* __restrict__ W,
                     const float* __restrict__ bias, const float* __restrict__ aux,
                     const float* __restrict__ lng, const float* __restrict__ lnb,
                     float* __restrict__ out, int r0, int nrows,
                     float* sWT, float (*sIn)[128])
{
  const int t = threadIdx.x;
  for(int idx=t; idx<2048; idx+=256){
    int r = idx>>7, c = idx&127;
    int row = r0+r;
    sIn[r][c] = (row<nrows) ? in[(size_t)row*128+c] : 0.f;
  }
  const int og = t & 31, rg = t >> 5;
  const int o0 = og*4;
  const float* s0p = sIn[rg*2];
  const float* s1p = sIn[rg*2+1];
  float4 a0 = make_float4(0,0,0,0), a1 = make_float4(0,0,0,0);

  #pragma unroll
  for(int half=0; half<2; half++){
    int c0 = half*64;
    __syncthreads();
    for(int idx=t; idx<8192; idx+=256){
      int o = idx>>6, cc = idx&63;
      sWT[cc*132 + o] = W[o*128 + c0 + cc];
    }
    __syncthreads();
    #pragma unroll 4
    for(int c=0;c<64;c+=4){
      float4 sA = *(const float4*)(s0p + c0 + c);
      float4 sB = *(const float4*)(s1p + c0 + c);
      const float* wp = sWT + c*132 + o0;
      float4 w0 = *(const float4*)(wp);
      float4 w1 = *(const float4*)(wp + 132);
      float4 w2 = *(const float4*)(wp + 264);
      float4 w3 = *(const float4*)(wp + 396);
      a0 = f4fma(a0, sA.x, w0); a0 = f4fma(a0, sA.y, w1);
      a0 = f4fma(a0, sA.z, w2); a0 = f4fma(a0, sA.w, w3);
      a1 = f4fma(a1, sB.x, w0); a1 = f4fma(a1, sB.y, w1);
      a1 = f4fma(a1, sB.z, w2); a1 = f4fma(a1, sB.w, w3);
    }
  }
  float4 bv = *(const float4*)(bias + o0);
  a0 = f4add(a0, bv); a1 = f4add(a1, bv);
  int row0 = r0 + rg*2, row1 = row0 + 1;

  if(EPI == 0){
    if(row0 < nrows) *(float4*)(out + (size_t)row0*128 + o0) = a0;
    if(row1 < nrows) *(float4*)(out + (size_t)row1*128 + o0) = a1;
  } else {
    const float* x0 = aux + ((row0>>8)&15)*128;
    const float* x1 = aux + ((row1>>8)&15)*128;
    a0 = f4add(a0, *(const float4*)(x0 + o0));
    a1 = f4add(a1, *(const float4*)(x1 + o0));
    float s0 = a0.x+a0.y+a0.z+a0.w, s1 = a1.x+a1.y+a1.z+a1.w;
    float q0 = a0.x*a0.x+a0.y*a0.y+a0.z*a0.z+a0.w*a0.w;
    float q1 = a1.x*a1.x+a1.y*a1.y+a1.z*a1.z+a1.w*a1.w;
    #pragma unroll
    for(int o=1;o<32;o<<=1){
      s0 += __shfl_xor(s0,o,64); q0 += __shfl_xor(q0,o,64);
      s1 += __shfl_xor(s1,o,64); q1 += __shfl_xor(q1,o,64);
    }
    float m0 = s0*0.0078125f, v0 = q0*0.0078125f - m0*m0;
    float m1 = s1*0.0078125f, v1 = q1*0.0078125f - m1*m1;
    float i0 = rsqrtf(v0+1e-5f), i1 = rsqrtf(v1+1e-5f);
    float4 g  = *(const float4*)(lng + o0);
    float4 b2 = *(const float4*)(lnb + o0);
    float4 y0, y1;
    y0.x=(a0.x-m0)*i0*g.x+b2.x; y0.y=(a0.y-m0)*i0*g.y+b2.y;
    y0.z=(a0.z-m0)*i0*g.z+b2.z; y0.w=(a0.w-m0)*i0*g.w+b2.w;
    y1.x=(a1.x-m1)*i1*g.x+b2.x; y1.y=(a1.y-m1)*i1*g.y+b2.y;
    y1.z=(a1.z-m1)*i1*g.z+b2.z; y1.w=(a1.w-m1)*i1*g.w+b2.w;
    int n0=(row0>>8)&15, b0=row0>>12, i0i=row0&255;
    int n1=(row1>>8)&15, b1=row1>>12, i1i=row1&255;
    float* p0 = out + ((((size_t)b0*256+i0i)*16+n0)<<7);
    float* p1 = out + ((((size_t)b1*256+i1i)*16+n1)<<7);
    *(float4*)(p0 + o0) = y0;
    *(float4*)(p1 + o0) = y1;
  }
}

template<int EPI>
__global__ __launch_bounds__(256) void gemm16_kernel(
  const float* __restrict__ in, const float* __restrict__ W,
  const float* __restrict__ bias, const float* __restrict__ aux,
  const float* __restrict__ lng, const float* __restrict__ lnb,
  float* __restrict__ out, int nrows)
{
  __shared__ float sWT[64*132];
  __shared__ float sIn[16][128];
  gemm16_body<EPI>(in, W, bias, aux, lng, lnb, out, blockIdx.x*16, nrows, sWT, sIn);
}

// one launch for the 4 independent projections: qk1(64), v1(64), k4(64), q4(1)
__global__ __launch_bounds__(256) void proj4_kernel(
  const float* __restrict__ in0, const float* __restrict__ W0, const float* __restrict__ b0, float* __restrict__ o0,
  const float* __restrict__ in1, const float* __restrict__ W1, const float* __restrict__ b1, float* __restrict__ o1,
  const float* __restrict__ in2, const float* __restrict__ W2, const float* __restrict__ b2, float* __restrict__ o2,
  const float* __restrict__ in3, const float* __restrict__ W3, const float* __restrict__ b3, float* __restrict__ o3)
{
  __shared__ float sWT[64*132];
  __shared__ float sIn[16][128];
  int bb = blockIdx.x;
  if(bb < 64)       gemm16_body<0>(in0,W0,b0,nullptr,nullptr,nullptr,o0, bb*16,      1024, sWT,sIn);
  else if(bb < 128) gemm16_body<0>(in1,W1,b1,nullptr,nullptr,nullptr,o1,(bb-64)*16,  1024, sWT,sIn);
  else if(bb < 192) gemm16_body<0>(in2,W2,b2,nullptr,nullptr,nullptr,o2,(bb-128)*16, 1024, sWT,sIn);
  else              gemm16_body<0>(in3,W3,b3,nullptr,nullptr,nullptr,o3, 0,          16,   sWT,sIn);
}

// ===== fused: p = LN(a1o@Wo^T + bo + resid); v4 = p@Wv^T + bv  (16 rows/blk)
__global__ __launch_bounds__(256) void gemm_p_v4(
  const float* __restrict__ in, const float* __restrict__ Wo, const float* __restrict__ bo,
  const float* __restrict__ resid, const float* __restrict__ lng, const float* __restrict__ lnb,
  float* __restrict__ pout,
  const float* __restrict__ Wv, const float* __restrict__ bvv, float* __restrict__ v4out)
{
  __shared__ float sWT[64*132];
  __shared__ float sIn[16][128];
  const int t = threadIdx.x;
  const int r0 = blockIdx.x*16;
  for(int idx=t; idx<2048; idx+=256){
    int r = idx>>7, c = idx&127;
    sIn[r][c] = in[(size_t)(r0+r)*128+c];
  }
  const int og = t & 31, rg = t >> 5;
  const int o0 = og*4;
  const float* s0p = sIn[rg*2];
  const float* s1p = sIn[rg*2+1];
  float4 a0 = make_float4(0,0,0,0), a1 = make_float4(0,0,0,0);

  // ---- Phase A: x = a1o @ Wo^T ----
  #pragma unroll
  for(int half=0; half<2; half++){
    int c0 = half*64;
    __syncthreads();
    for(int idx=t; idx<8192; idx+=256){
      int o = idx>>6, cc = idx&63;
      sWT[cc*132 + o] = Wo[o*128 + c0 + cc];
    }
    __syncthreads();
    #pragma unroll 4
    for(int c=0;c<64;c+=4){
      float4 sA = *(const float4*)(s0p + c0 + c);
      float4 sB = *(const float4*)(s1p + c0 + c);
      const float* wp = sWT + c*132 + o0;
      float4 w0 = *(const float4*)(wp);
      float4 w1 = *(const float4*)(wp + 132);
      float4 w2 = *(const float4*)(wp + 264);
      float4 w3 = *(const float4*)(wp + 396);
      a0 = f4fma(a0, sA.x, w0); a0 = f4fma(a0, sA.y, w1);
      a0 = f4fma(a0, sA.z, w2); a0 = f4fma(a0, sA.w, w3);
      a1 = f4fma(a1, sB.x, w0); a1 = f4fma(a1, sB.y, w1);
      a1 = f4fma(a1, sB.z, w2); a1 = f4fma(a1, sB.w, w3);
    }
  }
  int row0 = r0 + rg*2, row1 = row0 + 1;
  {
    float4 bv = *(const float4*)(bo + o0);
    a0 = f4add(a0, bv); a1 = f4add(a1, bv);
    a0 = f4add(a0, *(const float4*)(resid + (size_t)row0*128 + o0));
    a1 = f4add(a1, *(const float4*)(resid + (size_t)row1*128 + o0));
    float s0 = a0.x+a0.y+a0.z+a0.w, s1 = a1.x+a1.y+a1.z+a1.w;
    float q0 = a0.x*a0.x+a0.y*a0.y+a0.z*a0.z+a0.w*a0.w;
    float q1 = a1.x*a1.x+a1.y*a1.y+a1.z*a1.z+a1.w*a1.w;
    #pragma unroll
    for(int o=1;o<32;o<<=1){
      s0 += __shfl_xor(s0,o,64); q0 += __shfl_xor(q0,o,64);
      s1 += __shfl_xor(s1,o,64); q1 += __shfl_xor(q1,o,64);
    }
    float m0 = s0*0.0078125f, v0 = q0*0.0078125f - m0*m0;
    float m1 = s1*0.0078125f, v1 = q1*0.0078125f - m1*m1;
    float i0 = rsqrtf(v0+1e-5f), i1 = rsqrtf(v1+1e-5f);
    float4 g  = *(const float4*)(lng + o0);
    float4 b2 = *(const float4*)(lnb + o0);
    float4 y0, y1;
    y0.x=(a0.x-m0)*i0*g.x+b2.x; y0.y=(a0.y-m0)*i0*g.y+b2.y;
    y0.z=(a0.z-m0)*i0*g.z+b2.z; y0.w=(a0.w-m0)*i0*g.w+b2.w;
    y1.x=(a1.x-m1)*i1*g.x+b2.x; y1.y=(a1.y-m1)*i1*g.y+b2.y;
    y1.z=(a1.z-m1)*i1*g.z+b2.z; y1.w=(a1.w-m1)*i1*g.w+b2.w;
    *(float4*)(pout + (size_t)row0*128 + o0) = y0;
    *(float4*)(pout + (size_t)row1*128 + o0) = y1;
    __syncthreads();                     // all Phase-A sIn reads done
    *(float4*)&sIn[rg*2  ][o0] = y0;     // p tile into LDS for Phase B
    *(float4*)&sIn[rg*2+1][o0] = y1;
  }

  // ---- Phase B: v4 = p @ Wv^T + bv ----
  a0 = make_float4(0,0,0,0); a1 = make_float4(0,0,0,0);
  #pragma unroll
  for(int half=0; half<2; half++){
    int c0 = half*64;
    __syncthreads();
    for(int idx=t; idx<8192; idx+=256){
      int o = idx>>6, cc = idx&63;
      sWT[cc*132 + o] = Wv[o*128 + c0 + cc];
    }
    __syncthreads();
    #pragma unroll 4
    for(int c=0;c<64;c+=4){
      float4 sA = *(const float4*)(s0p + c0 + c);
      float4 sB = *(const float4*)(s1p + c0 + c);
      const float* wp = sWT + c*132 + o0;
      float4 w0 = *(const float4*)(wp);
      float4 w1 = *(const float4*)(wp + 132);
      float4 w2 = *(const float4*)(wp + 264);
      float4 w3 = *(const float4*)(wp + 396);
      a0 = f4fma(a0, sA.x, w0); a0 = f4fma(a0, sA.y, w1);
      a0 = f4fma(a0, sA.z, w2); a0 = f4fma(a0, sA.w, w3);
      a1 = f4fma(a1, sB.x, w0); a1 = f4fma(a1, sB.y, w1);
      a1 = f4fma(a1, sB.z, w2); a1 = f4fma(a1, sB.w, w3);
    }
  }
  float4 bv2 = *(const float4*)(bvv + o0);
  a0 = f4add(a0, bv2); a1 = f4add(a1, bv2);
  *(float4*)(v4out + (size_t)row0*128 + o0) = a0;
  *(float4*)(v4out + (size_t)row1*128 + o0) = a1;
}

// ---------- Layer-1 attention: wave-per-row ----------
__global__ __launch_bounds__(256) void attn1_kernel(
  const float* __restrict__ qk, const float* __restrict__ v1,
  const float* __restrict__ gamma, float* __restrict__ qs, float* __restrict__ aout)
{
  __shared__ float psW[4][256];
  int tile = blockIdx.x & 15;
  int bh   = blockIdx.x >> 4;
  int b = bh >> 3, h = bh & 7;
  int t = threadIdx.x, lane = t & 63, w = t >> 6;
  int d = lane & 15, jg = lane >> 4;
  int j0 = 4*lane;

  float4 kreg[4][4];
  #pragma unroll
  for(int u=0;u<4;u++){
    const float4* kr = (const float4*)(qk + (b*256 + j0 + u)*128 + h*16);
    kreg[u][0]=kr[0]; kreg[u][1]=kr[1]; kreg[u][2]=kr[2]; kreg[u][3]=kr[3];
  }
  float vreg[64];
  const float* vbase = v1 + (b*256 + jg*64)*128 + h*16 + d;
  #pragma unroll
  for(int k=0;k<64;k++) vreg[k] = vbase[k*128];

  float ga = fabsf(gamma[h]);

  for(int r=0;r<4;r++){
    int i = tile*16 + w*4 + r;
    const float4* qr = (const float4*)(qk + (b*256 + i)*128 + h*16);
    float4 q0=qr[0], q1=qr[1], q2=qr[2], q3=qr[3];

    float raw[4]; float mloc = -3e38f;
    #pragma unroll
    for(int u=0;u<4;u++){
      const float4* kk = kreg[u];
      float s = q0.x*kk[0].x + q0.y*kk[0].y + q0.z*kk[0].z + q0.w*kk[0].w
              + q1.x*kk[1].x + q1.y*kk[1].y + q1.z*kk[1].z + q1.w*kk[1].w
              + q2.x*kk[2].x + q2.y*kk[2].y + q2.z*kk[2].z + q2.w*kk[2].w
              + q3.x*kk[3].x + q3.y*kk[3].y + q3.z*kk[3].z + q3.w*kk[3].w;
      raw[u] = s * 0.25f;
      if(j0+u <= i) mloc = fmaxf(mloc, raw[u]);
    }
    float m1 = waveAllMax(mloc);
    float e[4], c[4]; float lsum = 0.f;
    #pragma unroll
    for(int u=0;u<4;u++){
      e[u] = (j0+u <= i) ? __expf(raw[u]-m1) : 0.f;
      lsum += e[u]; c[u] = lsum;
    }
    float s = lsum;
    #pragma unroll
    for(int o=1;o<64;o<<=1){ float tv = __shfl_up(s,o,64); if(lane>=o) s += tv; }
    float pre = s - lsum;
    float tot = __shfl(s, 63, 64);
    float invtot = 1.f/tot;

    float s2v[4]; float m2loc = -3e38f;
    #pragma unroll
    for(int u=0;u<4;u++){
      int j = j0+u;
      float cum  = (pre + c[u]) * invtot;
      float remn = fmaxf(1.f - cum, 0.f);
      float dist = sqrtf(remn * fabsf((float)(j - i)));
      float eff  = fminf(fmaxf(__expf(-ga*dist), 1e-5f), 1e5f);
      s2v[u] = raw[u]*eff;
      if(j <= i) m2loc = fmaxf(m2loc, s2v[u]);
    }
    float m2 = waveAllMax(m2loc);
    float e2[4]; float zloc = 0.f;
    #pragma unroll
    for(int u=0;u<4;u++){
      e2[u] = (j0+u <= i) ? __expf(s2v[u]-m2) : 0.f;
      zloc += e2[u];
    }
    float Z = waveAllSum(zloc);
    float invZ = 1.f/Z;
    float p0=e2[0]*invZ, p1=e2[1]*invZ, p2=e2[2]*invZ, p3=e2[3]*invZ;

    *(float4*)(qs + ((size_t)(bh*256 + i))*256 + j0) = make_float4(p0,p1,p2,p3);

    __syncthreads();
    *(float4*)&psW[w][j0] = make_float4(p0,p1,p2,p3);
    __syncthreads();
    float acc = 0.f;
    const float4* pw = (const float4*)&psW[w][jg*64];
    #pragma unroll
    for(int k=0;k<16;k++){
      float4 pk = pw[k];
      acc += pk.x*vreg[4*k] + pk.y*vreg[4*k+1] + pk.z*vreg[4*k+2] + pk.w*vreg[4*k+3];
    }
    acc += __shfl_xor(acc,16,64);
    acc += __shfl_xor(acc,32,64);
    if(lane < 16)
      aout[(b*256 + i)*128 + h*16 + d] = acc;
  }
}

DEV float dot16(const float* a, const float* b){
  float s = 0.f;
  #pragma unroll
  for(int k=0;k<16;k++) s += a[k]*b[k];
  return s;
}

// ---------- Layer-4 main with fused prefix scan ----------
// grid: 1024 = 512 bnh * 2 halves; block 256 = 4 waves
__global__ __launch_bounds__(256) void attn4_main(
  const float* __restrict__ q4, const float* __restrict__ k4,
  const float* __restrict__ v4, const float* __restrict__ gamma,
  float* __restrict__ ks, float* __restrict__ aout)
{
  __shared__ float sc4[4];
  __shared__ float rawL[256];
  __shared__ float PL[256];
  __shared__ float psW[4][256];
  int half = blockIdx.x & 1;
  int bnh  = blockIdx.x >> 1;
  int b = bnh >> 7, n = (bnh >> 3) & 15, h = bnh & 7;
  int t = threadIdx.x, lane = t & 63, w = t >> 6;
  int d = lane & 15, jg = lane >> 4;
  int j0 = 4*lane;

  // fused attn4_pre: raw[j] and prefix P[j] of exp(raw - M), in LDS
  {
    const float* qrow = q4 + n*128 + h*16;
    const float* krow = k4 + (b*256 + t)*128 + h*16;
    float raw = dot16(qrow, krow) * 0.25f;
    float M = blockMax256(raw, sc4);
    float E = __expf(raw - M);
    float tot;
    float P = blockScan256(E, sc4, tot);
    rawL[t] = raw;
    PL[t]   = P;
  }
  // V panel in registers
  float vreg[64];
  const float* vbase = v4 + (b*256 + jg*64)*128 + h*16 + d;
  #pragma unroll
  for(int k=0;k<64;k++) vreg[k] = vbase[k*128];
  __syncthreads();

  float4 rw = *(const float4*)(rawL + j0);
  float4 Pv = *(const float4*)(PL + j0);
  float P_[4] = {Pv.x, Pv.y, Pv.z, Pv.w};
  float R_[4] = {rw.x, rw.y, rw.z, rw.w};

  float g4a = fabsf(gamma[h]);
  size_t ksrowbase = ((size_t)(b*8 + h)*256)*4096 + (size_t)n*256 + j0;

  for(int r=0;r<32;r++){
    int i = half*128 + w*32 + r;     // wave-uniform
    float p0=0.f,p1=0.f,p2=0.f,p3=0.f;
    if(i > 0){
      float invPm1 = 1.f / PL[i-1];  // LDS broadcast
      float s2v[4]; float mloc = -3e38f;
      #pragma unroll
      for(int u=0;u<4;u++){
        int j = j0+u;
        float cum  = P_[u]*invPm1;
        float remn = fmaxf(1.f - cum, 0.f);
        float dist = sqrtf(remn * fabsf((float)(j - i)));
        float eff  = fminf(fmaxf(__expf(-g4a*dist), 1e-5f), 1e5f);
        float s2   = R_[u]*eff;
        s2v[u] = s2;
        if(j < i) mloc = fmaxf(mloc, s2);
      }
      float m2 = waveAllMax(mloc);
      float e_[4]; float zloc = 0.f;
      #pragma unroll
      for(int u=0;u<4;u++){
        float e = (j0+u < i) ? __expf(s2v[u]-m2) : 0.f;
        e_[u] = e; zloc += e;
      }
      float Z = waveAllSum(zloc);
      float sc = fminf(Z, 5.f)/Z;    // maxout: max(p)=1/Z
      p0=e_[0]*sc; p1=e_[1]*sc; p2=e_[2]*sc; p3=e_[3]*sc;
    }
    *(float4*)(ks + ksrowbase + (size_t)i*4096) = make_float4(p0,p1,p2,p3);

    __syncthreads();
    *(float4*)&psW[w][j0] = make_float4(p0,p1,p2,p3);
    __syncthreads();
    float acc = 0.f;
    const float4* pw = (const float4*)&psW[w][jg*64];
    #pragma unroll
    for(int k=0;k<16;k++){
      float4 pk = pw[k];
      acc += pk.x*vreg[4*k] + pk.y*vreg[4*k+1] + pk.z*vreg[4*k+2] + pk.w*vreg[4*k+3];
    }
    acc += __shfl_xor(acc,16,64);
    acc += __shfl_xor(acc,32,64);
    if(lane < 16)
      aout[((b*16+n)*256 + i)*128 + h*16 + d] = acc;
  }
}

extern "C" void kernel_launch(void* const* d_in, const int* in_sizes, int n_in,
                              void* d_out, int out_size, void* d_ws, size_t ws_size,
                              hipStream_t stream)
{
  (void)in_sizes; (void)n_in; (void)out_size; (void)ws_size;
  const float* q_emb   = (const float*)d_in[0];
  const float* s_emb   = (const float*)d_in[1];
  const float* b1_Wq   = (const float*)d_in[3];
  const float* b1_bq   = (const float*)d_in[4];
  const float* b1_Wv   = (const float*)d_in[5];
  const float* b1_bv   = (const float*)d_in[6];
  const float* b1_Wo   = (const float*)d_in[7];
  const float* b1_bo   = (const float*)d_in[8];
  const float* b1_gamma= (const float*)d_in[9];
  const float* b1_lng  = (const float*)d_in[10];
  const float* b1_lnb  = (const float*)d_in[11];
  const float* b4_Wq   = (const float*)d_in[12];
  const float* b4_bq   = (const float*)d_in[13];
  const float* b4_Wk   = (const float*)d_in[14];
  const float* b4_bk   = (const float*)d_in[15];
  const float* b4_Wv   = (const float*)d_in[16];
  const float* b4_bv   = (const float*)d_in[17];
  const float* b4_Wo   = (const float*)d_in[18];
  const float* b4_bo   = (const float*)d_in[19];
  const float* b4_gamma= (const float*)d_in[20];
  const float* b4_lng  = (const float*)d_in[21];
  const float* b4_lnb  = (const float*)d_in[22];
  const float* know    = (const float*)d_in[23];

  float* w    = (float*)d_ws;
  float* qk1  = w;                 // 131072
  float* v1   = w + 131072;        // 131072
  float* a1o  = w + 262144;        // 131072
  float* p    = w + 393216;        // 131072
  float* q4   = w + 524288;        // 2048
  float* k4   = w + 526336;        // 131072
  float* v4   = w + 657408;        // 131072
  float* a4o  = w + 788480;        // 2097152

  float* z_out  = (float*)d_out;                 // (4,256,2048)
  float* qs_out = z_out + 2097152;               // (4,8,256,256)
  float* ks_out = z_out + 4194304;               // (4,8,256,16,256)

  // L1: fused projections qk1, v1, k4, q4
  proj4_kernel<<<193,256,0,stream>>>(
      q_emb, b1_Wq, b1_bq, qk1,
      s_emb, b1_Wv, b1_bv, v1,
      q_emb, b4_Wk, b4_bk, k4,
      know,  b4_Wq, b4_bq, q4);

  // L2: layer-1 attention
  attn1_kernel<<<512,256,0,stream>>>(qk1, v1, b1_gamma, qs_out, a1o);

  // L3: p = LN(a1o@Wo+bo+q_emb); v4 = p@Wv+bv   (fused)
  gemm_p_v4<<<64,256,0,stream>>>(a1o, b1_Wo, b1_bo, q_emb, b1_lng, b1_lnb, p,
                                 b4_Wv, b4_bv, v4);

  // L4: layer-4 attention (scan fused in)
  attn4_main<<<1024,256,0,stream>>>(q4, k4, v4, b4_gamma, ks_out, a4o);

  // L5: z projection + LN
  gemm16_kernel<2><<<1024,256,0,stream>>>(a4o, b4_Wo, b4_bo, know, b4_lng, b4_lnb, z_out, 16384);
}

// Round 7
// 305.001 us; speedup vs baseline: 2.3278x; 1.0112x over previous
//
#include <hip/hip_runtime.h>

#define DEV __device__ __forceinline__

DEV float4 f4fma(float4 a, float s, float4 w){
  a.x = fmaf(s, w.x, a.x); a.y = fmaf(s, w.y, a.y);
  a.z = fmaf(s, w.z, a.z); a.w = fmaf(s, w.w, a.w);
  return a;
}
DEV float4 f4add(float4 a, float4 b){
  a.x+=b.x; a.y+=b.y; a.z+=b.z; a.w+=b.w; return a;
}

// ---------- wave (64-lane) butterflies ----------
DEV float waveAllMax(float x){
  #pragma unroll
  for(int o=1;o<64;o<<=1) x = fmaxf(x, __shfl_xor(x,o,64));
  return x;
}
DEV float waveAllSum(float x){
  #pragma unroll
  for(int o=1;o<64;o<<=1) x += __shfl_xor(x,o,64);
  return x;
}
DEV float waveReduceMax(float x){
  #pragma unroll
  for(int o=32;o>0;o>>=1) x = fmaxf(x, __shfl_down(x,o,64));
  return x;
}
// ---------- 256-thread block helpers ----------
DEV float blockMax256(float x, float* sc){
  int lane = threadIdx.x & 63, wid = threadIdx.x >> 6;
  x = waveReduceMax(x);
  __syncthreads();
  if(lane==0) sc[wid] = x;
  __syncthreads();
  return fmaxf(fmaxf(sc[0],sc[1]), fmaxf(sc[2],sc[3]));
}
DEV float blockScan256(float x, float* sc, float& total){
  int lane = threadIdx.x & 63, wid = threadIdx.x >> 6;
  float v = x;
  #pragma unroll
  for(int o=1;o<64;o<<=1){ float t = __shfl_up(v,o,64); if(lane>=o) v += t; }
  __syncthreads();
  if(lane==63) sc[wid] = v;
  __syncthreads();
  float pre=0.f, tot=0.f;
  #pragma unroll
  for(int ww=0;ww<4;ww++){ float s = sc[ww]; tot += s; if(ww<wid) pre += s; }
  total = tot;
  return v + pre;
}

// ================= GEMM16: out(16x128) = in @ W^T + b ======================
// EPI 0: plain store. EPI 2: +aux[n] (know), LN, scatter to z layout (b,i,n,c).
template<int EPI>
DEV void gemm16_body(const float* __restrict__ in, const float* __restrict__ W,
                     const float* __restrict__ bias, const float* __restrict__ aux,
                     const float* __restrict__ lng, const float* __restrict__ lnb,
                     float* __restrict__ out, int r0, int nrows,
                     float* sWT, float (*sIn)[128])
{
  const int t = threadIdx.x;
  for(int idx=t; idx<2048; idx+=256){
    int r = idx>>7, c = idx&127;
    int row = r0+r;
    sIn[r][c] = (row<nrows) ? in[(size_t)row*128+c] : 0.f;
  }
  const int og = t & 31, rg = t >> 5;
  const int o0 = og*4;
  const float* s0p = sIn[rg*2];
  const float* s1p = sIn[rg*2+1];
  float4 a0 = make_float4(0,0,0,0), a1 = make_float4(0,0,0,0);

  #pragma unroll
  for(int half=0; half<2; half++){
    int c0 = half*64;
    __syncthreads();
    for(int idx=t; idx<8192; idx+=256){
      int o = idx>>6, cc = idx&63;
      sWT[cc*132 + o] = W[o*128 + c0 + cc];
    }
    __syncthreads();
    #pragma unroll 4
    for(int c=0;c<64;c+=4){
      float4 sA = *(const float4*)(s0p + c0 + c);
      float4 sB = *(const float4*)(s1p + c0 + c);
      const float* wp = sWT + c*132 + o0;
      float4 w0 = *(const float4*)(wp);
      float4 w1 = *(const float4*)(wp + 132);
      float4 w2 = *(const float4*)(wp + 264);
      float4 w3 = *(const float4*)(wp + 396);
      a0 = f4fma(a0, sA.x, w0); a0 = f4fma(a0, sA.y, w1);
      a0 = f4fma(a0, sA.z, w2); a0 = f4fma(a0, sA.w, w3);
      a1 = f4fma(a1, sB.x, w0); a1 = f4fma(a1, sB.y, w1);
      a1 = f4fma(a1, sB.z, w2); a1 = f4fma(a1, sB.w, w3);
    }
  }
  float4 bv = *(const float4*)(bias + o0);
  a0 = f4add(a0, bv); a1 = f4add(a1, bv);
  int row0 = r0 + rg*2, row1 = row0 + 1;

  if(EPI == 0){
    if(row0 < nrows) *(float4*)(out + (size_t)row0*128 + o0) = a0;
    if(row1 < nrows) *(float4*)(out + (size_t)row1*128 + o0) = a1;
  } else {
    const float* x0 = aux + ((row0>>8)&15)*128;
    const float* x1 = aux + ((row1>>8)&15)*128;
    a0 = f4add(a0, *(const float4*)(x0 + o0));
    a1 = f4add(a1, *(const float4*)(x1 + o0));
    float s0 = a0.x+a0.y+a0.z+a0.w, s1 = a1.x+a1.y+a1.z+a1.w;
    float q0 = a0.x*a0.x+a0.y*a0.y+a0.z*a0.z+a0.w*a0.w;
    float q1 = a1.x*a1.x+a1.y*a1.y+a1.z*a1.z+a1.w*a1.w;
    #pragma unroll
    for(int o=1;o<32;o<<=1){
      s0 += __shfl_xor(s0,o,64); q0 += __shfl_xor(q0,o,64);
      s1 += __shfl_xor(s1,o,64); q1 += __shfl_xor(q1,o,64);
    }
    float m0 = s0*0.0078125f, v0 = q0*0.0078125f - m0*m0;
    float m1 = s1*0.0078125f, v1 = q1*0.0078125f - m1*m1;
    float i0 = rsqrtf(v0+1e-5f), i1 = rsqrtf(v1+1e-5f);
    float4 g  = *(const float4*)(lng + o0);
    float4 b2 = *(const float4*)(lnb + o0);
    float4 y0, y1;
    y0.x=(a0.x-m0)*i0*g.x+b2.x; y0.y=(a0.y-m0)*i0*g.y+b2.y;
    y0.z=(a0.z-m0)*i0*g.z+b2.z; y0.w=(a0.w-m0)*i0*g.w+b2.w;
    y1.x=(a1.x-m1)*i1*g.x+b2.x; y1.y=(a1.y-m1)*i1*g.y+b2.y;
    y1.z=(a1.z-m1)*i1*g.z+b2.z; y1.w=(a1.w-m1)*i1*g.w+b2.w;
    int n0=(row0>>8)&15, b0=row0>>12, i0i=row0&255;
    int n1=(row1>>8)&15, b1=row1>>12, i1i=row1&255;
    float* p0 = out + ((((size_t)b0*256+i0i)*16+n0)<<7);
    float* p1 = out + ((((size_t)b1*256+i1i)*16+n1)<<7);
    *(float4*)(p0 + o0) = y0;
    *(float4*)(p1 + o0) = y1;
  }
}

template<int EPI>
__global__ __launch_bounds__(256) void gemm16_kernel(
  const float* __restrict__ in, const float* __restrict__ W,
  const float* __restrict__ bias, const float* __restrict__ aux,
  const float* __restrict__ lng, const float* __restrict__ lnb,
  float* __restrict__ out, int nrows)
{
  __shared__ float sWT[64*132];
  __shared__ float sIn[16][128];
  gemm16_body<EPI>(in, W, bias, aux, lng, lnb, out, blockIdx.x*16, nrows, sWT, sIn);
}

// one launch for the 4 independent projections: qk1(64), v1(64), k4(64), q4(1)
__global__ __launch_bounds__(256) void proj4_kernel(
  const float* __restrict__ in0, const float* __restrict__ W0, const float* __restrict__ b0, float* __restrict__ o0,
  const float* __restrict__ in1, const float* __restrict__ W1, const float* __restrict__ b1, float* __restrict__ o1,
  const float* __restrict__ in2, const float* __restrict__ W2, const float* __restrict__ b2, float* __restrict__ o2,
  const float* __restrict__ in3, const float* __restrict__ W3, const float* __restrict__ b3, float* __restrict__ o3)
{
  __shared__ float sWT[64*132];
  __shared__ float sIn[16][128];
  int bb = blockIdx.x;
  if(bb < 64)       gemm16_body<0>(in0,W0,b0,nullptr,nullptr,nullptr,o0, bb*16,      1024, sWT,sIn);
  else if(bb < 128) gemm16_body<0>(in1,W1,b1,nullptr,nullptr,nullptr,o1,(bb-64)*16,  1024, sWT,sIn);
  else if(bb < 192) gemm16_body<0>(in2,W2,b2,nullptr,nullptr,nullptr,o2,(bb-128)*16, 1024, sWT,sIn);
  else              gemm16_body<0>(in3,W3,b3,nullptr,nullptr,nullptr,o3, 0,          16,   sWT,sIn);
}

// ===== fused: p = LN(a1o@Wo^T + bo + resid); v4 = p@Wv^T + bv  (16 rows/blk)
__global__ __launch_bounds__(256) void gemm_p_v4(
  const float* __restrict__ in, const float* __restrict__ Wo, const float* __restrict__ bo,
  const float* __restrict__ resid, const float* __restrict__ lng, const float* __restrict__ lnb,
  float* __restrict__ pout,
  const float* __restrict__ Wv, const float* __restrict__ bvv, float* __restrict__ v4out)
{
  __shared__ float sWT[64*132];
  __shared__ float sIn[16][128];
  const int t = threadIdx.x;
  const int r0 = blockIdx.x*16;
  for(int idx=t; idx<2048; idx+=256){
    int r = idx>>7, c = idx&127;
    sIn[r][c] = in[(size_t)(r0+r)*128+c];
  }
  const int og = t & 31, rg = t >> 5;
  const int o0 = og*4;
  const float* s0p = sIn[rg*2];
  const float* s1p = sIn[rg*2+1];
  float4 a0 = make_float4(0,0,0,0), a1 = make_float4(0,0,0,0);

  // ---- Phase A: x = a1o @ Wo^T ----
  #pragma unroll
  for(int half=0; half<2; half++){
    int c0 = half*64;
    __syncthreads();
    for(int idx=t; idx<8192; idx+=256){
      int o = idx>>6, cc = idx&63;
      sWT[cc*132 + o] = Wo[o*128 + c0 + cc];
    }
    __syncthreads();
    #pragma unroll 4
    for(int c=0;c<64;c+=4){
      float4 sA = *(const float4*)(s0p + c0 + c);
      float4 sB = *(const float4*)(s1p + c0 + c);
      const float* wp = sWT + c*132 + o0;
      float4 w0 = *(const float4*)(wp);
      float4 w1 = *(const float4*)(wp + 132);
      float4 w2 = *(const float4*)(wp + 264);
      float4 w3 = *(const float4*)(wp + 396);
      a0 = f4fma(a0, sA.x, w0); a0 = f4fma(a0, sA.y, w1);
      a0 = f4fma(a0, sA.z, w2); a0 = f4fma(a0, sA.w, w3);
      a1 = f4fma(a1, sB.x, w0); a1 = f4fma(a1, sB.y, w1);
      a1 = f4fma(a1, sB.z, w2); a1 = f4fma(a1, sB.w, w3);
    }
  }
  int row0 = r0 + rg*2, row1 = row0 + 1;
  {
    float4 bv = *(const float4*)(bo + o0);
    a0 = f4add(a0, bv); a1 = f4add(a1, bv);
    a0 = f4add(a0, *(const float4*)(resid + (size_t)row0*128 + o0));
    a1 = f4add(a1, *(const float4*)(resid + (size_t)row1*128 + o0));
    float s0 = a0.x+a0.y+a0.z+a0.w, s1 = a1.x+a1.y+a1.z+a1.w;
    float q0 = a0.x*a0.x+a0.y*a0.y+a0.z*a0.z+a0.w*a0.w;
    float q1 = a1.x*a1.x+a1.y*a1.y+a1.z*a1.z+a1.w*a1.w;
    #pragma unroll
    for(int o=1;o<32;o<<=1){
      s0 += __shfl_xor(s0,o,64); q0 += __shfl_xor(q0,o,64);
      s1 += __shfl_xor(s1,o,64); q1 += __shfl_xor(q1,o,64);
    }
    float m0 = s0*0.0078125f, v0 = q0*0.0078125f - m0*m0;
    float m1 = s1*0.0078125f, v1 = q1*0.0078125f - m1*m1;
    float i0 = rsqrtf(v0+1e-5f), i1 = rsqrtf(v1+1e-5f);
    float4 g  = *(const float4*)(lng + o0);
    float4 b2 = *(const float4*)(lnb + o0);
    float4 y0, y1;
    y0.x=(a0.x-m0)*i0*g.x+b2.x; y0.y=(a0.y-m0)*i0*g.y+b2.y;
    y0.z=(a0.z-m0)*i0*g.z+b2.z; y0.w=(a0.w-m0)*i0*g.w+b2.w;
    y1.x=(a1.x-m1)*i1*g.x+b2.x; y1.y=(a1.y-m1)*i1*g.y+b2.y;
    y1.z=(a1.z-m1)*i1*g.z+b2.z; y1.w=(a1.w-m1)*i1*g.w+b2.w;
    *(float4*)(pout + (size_t)row0*128 + o0) = y0;
    *(float4*)(pout + (size_t)row1*128 + o0) = y1;
    __syncthreads();                     // all Phase-A sIn reads done
    *(float4*)&sIn[rg*2  ][o0] = y0;     // p tile into LDS for Phase B
    *(float4*)&sIn[rg*2+1][o0] = y1;
  }

  // ---- Phase B: v4 = p @ Wv^T + bv ----
  a0 = make_float4(0,0,0,0); a1 = make_float4(0,0,0,0);
  #pragma unroll
  for(int half=0; half<2; half++){
    int c0 = half*64;
    __syncthreads();
    for(int idx=t; idx<8192; idx+=256){
      int o = idx>>6, cc = idx&63;
      sWT[cc*132 + o] = Wv[o*128 + c0 + cc];
    }
    __syncthreads();
    #pragma unroll 4
    for(int c=0;c<64;c+=4){
      float4 sA = *(const float4*)(s0p + c0 + c);
      float4 sB = *(const float4*)(s1p + c0 + c);
      const float* wp = sWT + c*132 + o0;
      float4 w0 = *(const float4*)(wp);
      float4 w1 = *(const float4*)(wp + 132);
      float4 w2 = *(const float4*)(wp + 264);
      float4 w3 = *(const float4*)(wp + 396);
      a0 = f4fma(a0, sA.x, w0); a0 = f4fma(a0, sA.y, w1);
      a0 = f4fma(a0, sA.z, w2); a0 = f4fma(a0, sA.w, w3);
      a1 = f4fma(a1, sB.x, w0); a1 = f4fma(a1, sB.y, w1);
      a1 = f4fma(a1, sB.z, w2); a1 = f4fma(a1, sB.w, w3);
    }
  }
  float4 bv2 = *(const float4*)(bvv + o0);
  a0 = f4add(a0, bv2); a1 = f4add(a1, bv2);
  *(float4*)(v4out + (size_t)row0*128 + o0) = a0;
  *(float4*)(v4out + (size_t)row1*128 + o0) = a1;
}

// ---------- Layer-1 attention: wave-per-row, barrier-free PV ----------
__global__ __launch_bounds__(256) void attn1_kernel(
  const float* __restrict__ qk, const float* __restrict__ v1,
  const float* __restrict__ gamma, float* __restrict__ qs, float* __restrict__ aout)
{
  __shared__ float psW[4][256];   // wave-private: psW[w] touched only by wave w
  int tile = blockIdx.x & 15;
  int bh   = blockIdx.x >> 4;
  int b = bh >> 3, h = bh & 7;
  int t = threadIdx.x, lane = t & 63, w = t >> 6;
  int d = lane & 15, jg = lane >> 4;
  int j0 = 4*lane;

  float4 kreg[4][4];
  #pragma unroll
  for(int u=0;u<4;u++){
    const float4* kr = (const float4*)(qk + (b*256 + j0 + u)*128 + h*16);
    kreg[u][0]=kr[0]; kreg[u][1]=kr[1]; kreg[u][2]=kr[2]; kreg[u][3]=kr[3];
  }
  float vreg[64];
  const float* vbase = v1 + (b*256 + jg*64)*128 + h*16 + d;
  #pragma unroll
  for(int k=0;k<64;k++) vreg[k] = vbase[k*128];

  float ga = fabsf(gamma[h]);

  for(int r=0;r<4;r++){
    int i = tile*16 + w*4 + r;
    const float4* qr = (const float4*)(qk + (b*256 + i)*128 + h*16);
    float4 q0=qr[0], q1=qr[1], q2=qr[2], q3=qr[3];

    float raw[4]; float mloc = -3e38f;
    #pragma unroll
    for(int u=0;u<4;u++){
      const float4* kk = kreg[u];
      float s = q0.x*kk[0].x + q0.y*kk[0].y + q0.z*kk[0].z + q0.w*kk[0].w
              + q1.x*kk[1].x + q1.y*kk[1].y + q1.z*kk[1].z + q1.w*kk[1].w
              + q2.x*kk[2].x + q2.y*kk[2].y + q2.z*kk[2].z + q2.w*kk[2].w
              + q3.x*kk[3].x + q3.y*kk[3].y + q3.z*kk[3].z + q3.w*kk[3].w;
      raw[u] = s * 0.25f;
      if(j0+u <= i) mloc = fmaxf(mloc, raw[u]);
    }
    float m1 = waveAllMax(mloc);
    float e[4], c[4]; float lsum = 0.f;
    #pragma unroll
    for(int u=0;u<4;u++){
      e[u] = (j0+u <= i) ? __expf(raw[u]-m1) : 0.f;
      lsum += e[u]; c[u] = lsum;
    }
    float s = lsum;
    #pragma unroll
    for(int o=1;o<64;o<<=1){ float tv = __shfl_up(s,o,64); if(lane>=o) s += tv; }
    float pre = s - lsum;
    float tot = __shfl(s, 63, 64);
    float invtot = 1.f/tot;

    float s2v[4]; float m2loc = -3e38f;
    #pragma unroll
    for(int u=0;u<4;u++){
      int j = j0+u;
      float cum  = (pre + c[u]) * invtot;
      float remn = fmaxf(1.f - cum, 0.f);
      float dist = sqrtf(remn * fabsf((float)(j - i)));
      float eff  = fminf(fmaxf(__expf(-ga*dist), 1e-5f), 1e5f);
      s2v[u] = raw[u]*eff;
      if(j <= i) m2loc = fmaxf(m2loc, s2v[u]);
    }
    float m2 = waveAllMax(m2loc);
    float e2[4]; float zloc = 0.f;
    #pragma unroll
    for(int u=0;u<4;u++){
      e2[u] = (j0+u <= i) ? __expf(s2v[u]-m2) : 0.f;
      zloc += e2[u];
    }
    float Z = waveAllSum(zloc);
    float invZ = 1.f/Z;
    float p0=e2[0]*invZ, p1=e2[1]*invZ, p2=e2[2]*invZ, p3=e2[3]*invZ;

    *(float4*)(qs + ((size_t)(bh*256 + i))*256 + j0) = make_float4(p0,p1,p2,p3);

    // wave-local LDS transpose: per-wave DS ops are in program order -> no barrier
    *(float4*)&psW[w][j0] = make_float4(p0,p1,p2,p3);
    float acc = 0.f;
    const float4* pw = (const float4*)&psW[w][jg*64];
    #pragma unroll
    for(int k=0;k<16;k++){
      float4 pk = pw[k];
      acc += pk.x*vreg[4*k] + pk.y*vreg[4*k+1] + pk.z*vreg[4*k+2] + pk.w*vreg[4*k+3];
    }
    acc += __shfl_xor(acc,16,64);
    acc += __shfl_xor(acc,32,64);
    if(lane < 16)
      aout[(b*256 + i)*128 + h*16 + d] = acc;
  }
}

DEV float dot16(const float* a, const float* b){
  float s = 0.f;
  #pragma unroll
  for(int k=0;k<16;k++) s += a[k]*b[k];
  return s;
}

// ---------- Layer-4 main: fused scan, barrier-free PV ----------
// grid: 1024 = 512 bnh * 2 halves; block 256 = 4 waves
__global__ __launch_bounds__(256) void attn4_main(
  const float* __restrict__ q4, const float* __restrict__ k4,
  const float* __restrict__ v4, const float* __restrict__ gamma,
  float* __restrict__ ks, float* __restrict__ aout)
{
  __shared__ float sc4[4];
  __shared__ float rawL[256];
  __shared__ float PL[256];
  __shared__ float psW[4][256];   // wave-private
  int half = blockIdx.x & 1;
  int bnh  = blockIdx.x >> 1;
  int b = bnh >> 7, n = (bnh >> 3) & 15, h = bnh & 7;
  int t = threadIdx.x, lane = t & 63, w = t >> 6;
  int d = lane & 15, jg = lane >> 4;
  int j0 = 4*lane;

  // fused attn4_pre: raw[j] and prefix P[j] of exp(raw - M), in LDS
  {
    const float* qrow = q4 + n*128 + h*16;
    const float* krow = k4 + (b*256 + t)*128 + h*16;
    float raw = dot16(qrow, krow) * 0.25f;
    float M = blockMax256(raw, sc4);
    float E = __expf(raw - M);
    float tot;
    float P = blockScan256(E, sc4, tot);
    rawL[t] = raw;
    PL[t]   = P;
  }
  // V panel in registers
  float vreg[64];
  const float* vbase = v4 + (b*256 + jg*64)*128 + h*16 + d;
  #pragma unroll
  for(int k=0;k<64;k++) vreg[k] = vbase[k*128];
  __syncthreads();   // rawL/PL visible to all waves (once)

  float4 rw = *(const float4*)(rawL + j0);
  float4 Pv = *(const float4*)(PL + j0);
  float P_[4] = {Pv.x, Pv.y, Pv.z, Pv.w};
  float R_[4] = {rw.x, rw.y, rw.z, rw.w};

  float g4a = fabsf(gamma[h]);
  size_t ksrowbase = ((size_t)(b*8 + h)*256)*4096 + (size_t)n*256 + j0;

  for(int r=0;r<32;r++){
    int i = half*128 + w*32 + r;     // wave-uniform
    float p0=0.f,p1=0.f,p2=0.f,p3=0.f;
    if(i > 0){
      float invPm1 = 1.f / PL[i-1];  // LDS broadcast (read-only region now)
      float s2v[4]; float mloc = -3e38f;
      #pragma unroll
      for(int u=0;u<4;u++){
        int j = j0+u;
        float cum  = P_[u]*invPm1;
        float remn = fmaxf(1.f - cum, 0.f);
        float dist = sqrtf(remn * fabsf((float)(j - i)));
        float eff  = fminf(fmaxf(__expf(-g4a*dist), 1e-5f), 1e5f);
        float s2   = R_[u]*eff;
        s2v[u] = s2;
        if(j < i) mloc = fmaxf(mloc, s2);
      }
      float m2 = waveAllMax(mloc);
      float e_[4]; float zloc = 0.f;
      #pragma unroll
      for(int u=0;u<4;u++){
        float e = (j0+u < i) ? __expf(s2v[u]-m2) : 0.f;
        e_[u] = e; zloc += e;
      }
      float Z = waveAllSum(zloc);
      float sc = fminf(5.f/Z, 1.f);  // maxout: max(p)=1/Z -> scale=min(Z,5)/Z
      p0=e_[0]*sc; p1=e_[1]*sc; p2=e_[2]*sc; p3=e_[3]*sc;
    }
    *(float4*)(ks + ksrowbase + (size_t)i*4096) = make_float4(p0,p1,p2,p3);

    // wave-local LDS transpose: no block barrier
    *(float4*)&psW[w][j0] = make_float4(p0,p1,p2,p3);
    float acc = 0.f;
    const float4* pw = (const float4*)&psW[w][jg*64];
    #pragma unroll
    for(int k=0;k<16;k++){
      float4 pk = pw[k];
      acc += pk.x*vreg[4*k] + pk.y*vreg[4*k+1] + pk.z*vreg[4*k+2] + pk.w*vreg[4*k+3];
    }
    acc += __shfl_xor(acc,16,64);
    acc += __shfl_xor(acc,32,64);
    if(lane < 16)
      aout[((b*16+n)*256 + i)*128 + h*16 + d] = acc;
  }
}

extern "C" void kernel_launch(void* const* d_in, const int* in_sizes, int n_in,
                              void* d_out, int out_size, void* d_ws, size_t ws_size,
                              hipStream_t stream)
{
  (void)in_sizes; (void)n_in; (void)out_size; (void)ws_size;
  const float* q_emb   = (const float*)d_in[0];
  const float* s_emb   = (const float*)d_in[1];
  const float* b1_Wq   = (const float*)d_in[3];
  const float* b1_bq   = (const float*)d_in[4];
  const float* b1_Wv   = (const float*)d_in[5];
  const float* b1_bv   = (const float*)d_in[6];
  const float* b1_Wo   = (const float*)d_in[7];
  const float* b1_bo   = (const float*)d_in[8];
  const float* b1_gamma= (const float*)d_in[9];
  const float* b1_lng  = (const float*)d_in[10];
  const float* b1_lnb  = (const float*)d_in[11];
  const float* b4_Wq   = (const float*)d_in[12];
  const float* b4_bq   = (const float*)d_in[13];
  const float* b4_Wk   = (const float*)d_in[14];
  const float* b4_bk   = (const float*)d_in[15];
  const float* b4_Wv   = (const float*)d_in[16];
  const float* b4_bv   = (const float*)d_in[17];
  const float* b4_Wo   = (const float*)d_in[18];
  const float* b4_bo   = (const float*)d_in[19];
  const float* b4_gamma= (const float*)d_in[20];
  const float* b4_lng  = (const float*)d_in[21];
  const float* b4_lnb  = (const float*)d_in[22];
  const float* know    = (const float*)d_in[23];

  float* w    = (float*)d_ws;
  float* qk1  = w;                 // 131072
  float* v1   = w + 131072;        // 131072
  float* a1o  = w + 262144;        // 131072
  float* p    = w + 393216;        // 131072
  float* q4   = w + 524288;        // 2048
  float* k4   = w + 526336;        // 131072
  float* v4   = w + 657408;        // 131072
  float* a4o  = w + 788480;        // 2097152

  float* z_out  = (float*)d_out;                 // (4,256,2048)
  float* qs_out = z_out + 2097152;               // (4,8,256,256)
  float* ks_out = z_out + 4194304;               // (4,8,256,16,256)

  // L1: fused projections qk1, v1, k4, q4
  proj4_kernel<<<193,256,0,stream>>>(
      q_emb, b1_Wq, b1_bq, qk1,
      s_emb, b1_Wv, b1_bv, v1,
      q_emb, b4_Wk, b4_bk, k4,
      know,  b4_Wq, b4_bq, q4);

  // L2: layer-1 attention
  attn1_kernel<<<512,256,0,stream>>>(qk1, v1, b1_gamma, qs_out, a1o);

  // L3: p = LN(a1o@Wo+bo+q_emb); v4 = p@Wv+bv   (fused)
  gemm_p_v4<<<64,256,0,stream>>>(a1o, b1_Wo, b1_bo, q_emb, b1_lng, b1_lnb, p,
                                 b4_Wv, b4_bv, v4);

  // L4: layer-4 attention (scan fused in)
  attn4_main<<<1024,256,0,stream>>>(q4, k4, v4, b4_gamma, ks_out, a4o);

  // L5: z projection + LN
  gemm16_kernel<2><<<1024,256,0,stream>>>(a4o, b4_Wo, b4_bo, know, b4_lng, b4_lnb, z_out, 16384);
}

// Round 8
// 304.147 us; speedup vs baseline: 2.3343x; 1.0028x over previous
//
#include <hip/hip_runtime.h>

#define DEV __device__ __forceinline__

DEV float4 f4fma(float4 a, float s, float4 w){
  a.x = fmaf(s, w.x, a.x); a.y = fmaf(s, w.y, a.y);
  a.z = fmaf(s, w.z, a.z); a.w = fmaf(s, w.w, a.w);
  return a;
}
DEV float4 f4add(float4 a, float4 b){
  a.x+=b.x; a.y+=b.y; a.z+=b.z; a.w+=b.w; return a;
}

// ---------- wave (64-lane) butterflies ----------
DEV float waveAllMax(float x){
  #pragma unroll
  for(int o=1;o<64;o<<=1) x = fmaxf(x, __shfl_xor(x,o,64));
  return x;
}
DEV float waveAllSum(float x){
  #pragma unroll
  for(int o=1;o<64;o<<=1) x += __shfl_xor(x,o,64);
  return x;
}
DEV float waveReduceMax(float x){
  #pragma unroll
  for(int o=32;o>0;o>>=1) x = fmaxf(x, __shfl_down(x,o,64));
  return x;
}
// ---------- 256-thread block helpers ----------
DEV float blockMax256(float x, float* sc){
  int lane = threadIdx.x & 63, wid = threadIdx.x >> 6;
  x = waveReduceMax(x);
  __syncthreads();
  if(lane==0) sc[wid] = x;
  __syncthreads();
  return fmaxf(fmaxf(sc[0],sc[1]), fmaxf(sc[2],sc[3]));
}
DEV float blockScan256(float x, float* sc, float& total){
  int lane = threadIdx.x & 63, wid = threadIdx.x >> 6;
  float v = x;
  #pragma unroll
  for(int o=1;o<64;o<<=1){ float t = __shfl_up(v,o,64); if(lane>=o) v += t; }
  __syncthreads();
  if(lane==63) sc[wid] = v;
  __syncthreads();
  float pre=0.f, tot=0.f;
  #pragma unroll
  for(int ww=0;ww<4;ww++){ float s = sc[ww]; tot += s; if(ww<wid) pre += s; }
  total = tot;
  return v + pre;
}

// ================= GEMM16: out(16x128) = in @ W^T + b ======================
// EPI 0: plain store. EPI 2: +aux[n] (know), LN, scatter to z layout (b,i,n,c).
template<int EPI>
DEV void gemm16_body(const float* __restrict__ in, const float* __restrict__ W,
                     const float* __restrict__ bias, const float* __restrict__ aux,
                     const float* __restrict__ lng, const float* __restrict__ lnb,
                     float* __restrict__ out, int r0, int nrows,
                     float* sWT, float (*sIn)[128])
{
  const int t = threadIdx.x;
  for(int idx=t; idx<2048; idx+=256){
    int r = idx>>7, c = idx&127;
    int row = r0+r;
    sIn[r][c] = (row<nrows) ? in[(size_t)row*128+c] : 0.f;
  }
  const int og = t & 31, rg = t >> 5;
  const int o0 = og*4;
  const float* s0p = sIn[rg*2];
  const float* s1p = sIn[rg*2+1];
  float4 a0 = make_float4(0,0,0,0), a1 = make_float4(0,0,0,0);

  #pragma unroll
  for(int half=0; half<2; half++){
    int c0 = half*64;
    __syncthreads();
    for(int idx=t; idx<8192; idx+=256){
      int o = idx>>6, cc = idx&63;
      sWT[cc*132 + o] = W[o*128 + c0 + cc];
    }
    __syncthreads();
    #pragma unroll 4
    for(int c=0;c<64;c+=4){
      float4 sA = *(const float4*)(s0p + c0 + c);
      float4 sB = *(const float4*)(s1p + c0 + c);
      const float* wp = sWT + c*132 + o0;
      float4 w0 = *(const float4*)(wp);
      float4 w1 = *(const float4*)(wp + 132);
      float4 w2 = *(const float4*)(wp + 264);
      float4 w3 = *(const float4*)(wp + 396);
      a0 = f4fma(a0, sA.x, w0); a0 = f4fma(a0, sA.y, w1);
      a0 = f4fma(a0, sA.z, w2); a0 = f4fma(a0, sA.w, w3);
      a1 = f4fma(a1, sB.x, w0); a1 = f4fma(a1, sB.y, w1);
      a1 = f4fma(a1, sB.z, w2); a1 = f4fma(a1, sB.w, w3);
    }
  }
  float4 bv = *(const float4*)(bias + o0);
  a0 = f4add(a0, bv); a1 = f4add(a1, bv);
  int row0 = r0 + rg*2, row1 = row0 + 1;

  if(EPI == 0){
    if(row0 < nrows) *(float4*)(out + (size_t)row0*128 + o0) = a0;
    if(row1 < nrows) *(float4*)(out + (size_t)row1*128 + o0) = a1;
  } else {
    const float* x0 = aux + ((row0>>8)&15)*128;
    const float* x1 = aux + ((row1>>8)&15)*128;
    a0 = f4add(a0, *(const float4*)(x0 + o0));
    a1 = f4add(a1, *(const float4*)(x1 + o0));
    float s0 = a0.x+a0.y+a0.z+a0.w, s1 = a1.x+a1.y+a1.z+a1.w;
    float q0 = a0.x*a0.x+a0.y*a0.y+a0.z*a0.z+a0.w*a0.w;
    float q1 = a1.x*a1.x+a1.y*a1.y+a1.z*a1.z+a1.w*a1.w;
    #pragma unroll
    for(int o=1;o<32;o<<=1){
      s0 += __shfl_xor(s0,o,64); q0 += __shfl_xor(q0,o,64);
      s1 += __shfl_xor(s1,o,64); q1 += __shfl_xor(q1,o,64);
    }
    float m0 = s0*0.0078125f, v0 = q0*0.0078125f - m0*m0;
    float m1 = s1*0.0078125f, v1 = q1*0.0078125f - m1*m1;
    float i0 = rsqrtf(v0+1e-5f), i1 = rsqrtf(v1+1e-5f);
    float4 g  = *(const float4*)(lng + o0);
    float4 b2 = *(const float4*)(lnb + o0);
    float4 y0, y1;
    y0.x=(a0.x-m0)*i0*g.x+b2.x; y0.y=(a0.y-m0)*i0*g.y+b2.y;
    y0.z=(a0.z-m0)*i0*g.z+b2.z; y0.w=(a0.w-m0)*i0*g.w+b2.w;
    y1.x=(a1.x-m1)*i1*g.x+b2.x; y1.y=(a1.y-m1)*i1*g.y+b2.y;
    y1.z=(a1.z-m1)*i1*g.z+b2.z; y1.w=(a1.w-m1)*i1*g.w+b2.w;
    int n0=(row0>>8)&15, b0=row0>>12, i0i=row0&255;
    int n1=(row1>>8)&15, b1=row1>>12, i1i=row1&255;
    float* p0 = out + ((((size_t)b0*256+i0i)*16+n0)<<7);
    float* p1 = out + ((((size_t)b1*256+i1i)*16+n1)<<7);
    *(float4*)(p0 + o0) = y0;
    *(float4*)(p1 + o0) = y1;
  }
}

template<int EPI>
__global__ __launch_bounds__(256) void gemm16_kernel(
  const float* __restrict__ in, const float* __restrict__ W,
  const float* __restrict__ bias, const float* __restrict__ aux,
  const float* __restrict__ lng, const float* __restrict__ lnb,
  float* __restrict__ out, int nrows)
{
  __shared__ float sWT[64*132];
  __shared__ float sIn[16][128];
  gemm16_body<EPI>(in, W, bias, aux, lng, lnb, out, blockIdx.x*16, nrows, sWT, sIn);
}

// one launch for the 4 independent projections: qk1(64), v1(64), k4(64), q4(1)
__global__ __launch_bounds__(256) void proj4_kernel(
  const float* __restrict__ in0, const float* __restrict__ W0, const float* __restrict__ b0, float* __restrict__ o0,
  const float* __restrict__ in1, const float* __restrict__ W1, const float* __restrict__ b1, float* __restrict__ o1,
  const float* __restrict__ in2, const float* __restrict__ W2, const float* __restrict__ b2, float* __restrict__ o2,
  const float* __restrict__ in3, const float* __restrict__ W3, const float* __restrict__ b3, float* __restrict__ o3)
{
  __shared__ float sWT[64*132];
  __shared__ float sIn[16][128];
  int bb = blockIdx.x;
  if(bb < 64)       gemm16_body<0>(in0,W0,b0,nullptr,nullptr,nullptr,o0, bb*16,      1024, sWT,sIn);
  else if(bb < 128) gemm16_body<0>(in1,W1,b1,nullptr,nullptr,nullptr,o1,(bb-64)*16,  1024, sWT,sIn);
  else if(bb < 192) gemm16_body<0>(in2,W2,b2,nullptr,nullptr,nullptr,o2,(bb-128)*16, 1024, sWT,sIn);
  else              gemm16_body<0>(in3,W3,b3,nullptr,nullptr,nullptr,o3, 0,          16,   sWT,sIn);
}

// ===== fused: p = LN(a1o@Wo^T + bo + resid); v4 = p@Wv^T + bv  (16 rows/blk)
__global__ __launch_bounds__(256) void gemm_p_v4(
  const float* __restrict__ in, const float* __restrict__ Wo, const float* __restrict__ bo,
  const float* __restrict__ resid, const float* __restrict__ lng, const float* __restrict__ lnb,
  float* __restrict__ pout,
  const float* __restrict__ Wv, const float* __restrict__ bvv, float* __restrict__ v4out)
{
  __shared__ float sWT[64*132];
  __shared__ float sIn[16][128];
  const int t = threadIdx.x;
  const int r0 = blockIdx.x*16;
  for(int idx=t; idx<2048; idx+=256){
    int r = idx>>7, c = idx&127;
    sIn[r][c] = in[(size_t)(r0+r)*128+c];
  }
  const int og = t & 31, rg = t >> 5;
  const int o0 = og*4;
  const float* s0p = sIn[rg*2];
  const float* s1p = sIn[rg*2+1];
  float4 a0 = make_float4(0,0,0,0), a1 = make_float4(0,0,0,0);

  // ---- Phase A: x = a1o @ Wo^T ----
  #pragma unroll
  for(int half=0; half<2; half++){
    int c0 = half*64;
    __syncthreads();
    for(int idx=t; idx<8192; idx+=256){
      int o = idx>>6, cc = idx&63;
      sWT[cc*132 + o] = Wo[o*128 + c0 + cc];
    }
    __syncthreads();
    #pragma unroll 4
    for(int c=0;c<64;c+=4){
      float4 sA = *(const float4*)(s0p + c0 + c);
      float4 sB = *(const float4*)(s1p + c0 + c);
      const float* wp = sWT + c*132 + o0;
      float4 w0 = *(const float4*)(wp);
      float4 w1 = *(const float4*)(wp + 132);
      float4 w2 = *(const float4*)(wp + 264);
      float4 w3 = *(const float4*)(wp + 396);
      a0 = f4fma(a0, sA.x, w0); a0 = f4fma(a0, sA.y, w1);
      a0 = f4fma(a0, sA.z, w2); a0 = f4fma(a0, sA.w, w3);
      a1 = f4fma(a1, sB.x, w0); a1 = f4fma(a1, sB.y, w1);
      a1 = f4fma(a1, sB.z, w2); a1 = f4fma(a1, sB.w, w3);
    }
  }
  int row0 = r0 + rg*2, row1 = row0 + 1;
  {
    float4 bv = *(const float4*)(bo + o0);
    a0 = f4add(a0, bv); a1 = f4add(a1, bv);
    a0 = f4add(a0, *(const float4*)(resid + (size_t)row0*128 + o0));
    a1 = f4add(a1, *(const float4*)(resid + (size_t)row1*128 + o0));
    float s0 = a0.x+a0.y+a0.z+a0.w, s1 = a1.x+a1.y+a1.z+a1.w;
    float q0 = a0.x*a0.x+a0.y*a0.y+a0.z*a0.z+a0.w*a0.w;
    float q1 = a1.x*a1.x+a1.y*a1.y+a1.z*a1.z+a1.w*a1.w;
    #pragma unroll
    for(int o=1;o<32;o<<=1){
      s0 += __shfl_xor(s0,o,64); q0 += __shfl_xor(q0,o,64);
      s1 += __shfl_xor(s1,o,64); q1 += __shfl_xor(q1,o,64);
    }
    float m0 = s0*0.0078125f, v0 = q0*0.0078125f - m0*m0;
    float m1 = s1*0.0078125f, v1 = q1*0.0078125f - m1*m1;
    float i0 = rsqrtf(v0+1e-5f), i1 = rsqrtf(v1+1e-5f);
    float4 g  = *(const float4*)(lng + o0);
    float4 b2 = *(const float4*)(lnb + o0);
    float4 y0, y1;
    y0.x=(a0.x-m0)*i0*g.x+b2.x; y0.y=(a0.y-m0)*i0*g.y+b2.y;
    y0.z=(a0.z-m0)*i0*g.z+b2.z; y0.w=(a0.w-m0)*i0*g.w+b2.w;
    y1.x=(a1.x-m1)*i1*g.x+b2.x; y1.y=(a1.y-m1)*i1*g.y+b2.y;
    y1.z=(a1.z-m1)*i1*g.z+b2.z; y1.w=(a1.w-m1)*i1*g.w+b2.w;
    *(float4*)(pout + (size_t)row0*128 + o0) = y0;
    *(float4*)(pout + (size_t)row1*128 + o0) = y1;
    __syncthreads();                     // all Phase-A sIn reads done
    *(float4*)&sIn[rg*2  ][o0] = y0;     // p tile into LDS for Phase B
    *(float4*)&sIn[rg*2+1][o0] = y1;
  }

  // ---- Phase B: v4 = p @ Wv^T + bv ----
  a0 = make_float4(0,0,0,0); a1 = make_float4(0,0,0,0);
  #pragma unroll
  for(int half=0; half<2; half++){
    int c0 = half*64;
    __syncthreads();
    for(int idx=t; idx<8192; idx+=256){
      int o = idx>>6, cc = idx&63;
      sWT[cc*132 + o] = Wv[o*128 + c0 + cc];
    }
    __syncthreads();
    #pragma unroll 4
    for(int c=0;c<64;c+=4){
      float4 sA = *(const float4*)(s0p + c0 + c);
      float4 sB = *(const float4*)(s1p + c0 + c);
      const float* wp = sWT + c*132 + o0;
      float4 w0 = *(const float4*)(wp);
      float4 w1 = *(const float4*)(wp + 132);
      float4 w2 = *(const float4*)(wp + 264);
      float4 w3 = *(const float4*)(wp + 396);
      a0 = f4fma(a0, sA.x, w0); a0 = f4fma(a0, sA.y, w1);
      a0 = f4fma(a0, sA.z, w2); a0 = f4fma(a0, sA.w, w3);
      a1 = f4fma(a1, sB.x, w0); a1 = f4fma(a1, sB.y, w1);
      a1 = f4fma(a1, sB.z, w2); a1 = f4fma(a1, sB.w, w3);
    }
  }
  float4 bv2 = *(const float4*)(bvv + o0);
  a0 = f4add(a0, bv2); a1 = f4add(a1, bv2);
  *(float4*)(v4out + (size_t)row0*128 + o0) = a0;
  *(float4*)(v4out + (size_t)row1*128 + o0) = a1;
}

// ---------- Layer-1 attention: wave-per-row, (d4,jg) PV partition ----------
// grid 512 = 32 bh * 16 tiles; wave w -> rows tile*16 + w*4 + r
__global__ __launch_bounds__(256) void attn1_kernel(
  const float* __restrict__ qk, const float* __restrict__ v1,
  const float* __restrict__ gamma, float* __restrict__ qs, float* __restrict__ aout)
{
  __shared__ float psW[4][320];   // wave-private, 16 chunks * 20 floats
  int tile = blockIdx.x & 15;
  int bh   = blockIdx.x >> 4;
  int b = bh >> 3, h = bh & 7;
  int t = threadIdx.x, lane = t & 63, w = t >> 6;
  int d4 = lane & 3, jg = lane >> 2;     // PV: 4 d per lane, 16 j per lane
  int j0 = 4*lane;

  float4 kreg[4][4];
  #pragma unroll
  for(int u=0;u<4;u++){
    const float4* kr = (const float4*)(qk + (b*256 + j0 + u)*128 + h*16);
    kreg[u][0]=kr[0]; kreg[u][1]=kr[1]; kreg[u][2]=kr[2]; kreg[u][3]=kr[3];
  }
  // V panel: lane (d4,jg) holds V[jg*16+jj][4d4..4d4+3]
  float4 vreg[16];
  #pragma unroll
  for(int jj=0;jj<16;jj++)
    vreg[jj] = *(const float4*)(v1 + (b*256 + jg*16 + jj)*128 + h*16 + d4*4);

  float ga = fabsf(gamma[h]);
  float* myChunk = &psW[w][(lane>>2)*20 + 4*(lane&3)];
  const float* pw = &psW[w][jg*20];

  for(int r=0;r<4;r++){
    int i = tile*16 + w*4 + r;
    const float4* qr = (const float4*)(qk + (b*256 + i)*128 + h*16);
    float4 q0=qr[0], q1=qr[1], q2=qr[2], q3=qr[3];

    float raw[4]; float mloc = -3e38f;
    #pragma unroll
    for(int u=0;u<4;u++){
      const float4* kk = kreg[u];
      float s = q0.x*kk[0].x + q0.y*kk[0].y + q0.z*kk[0].z + q0.w*kk[0].w
              + q1.x*kk[1].x + q1.y*kk[1].y + q1.z*kk[1].z + q1.w*kk[1].w
              + q2.x*kk[2].x + q2.y*kk[2].y + q2.z*kk[2].z + q2.w*kk[2].w
              + q3.x*kk[3].x + q3.y*kk[3].y + q3.z*kk[3].z + q3.w*kk[3].w;
      raw[u] = s * 0.25f;
      if(j0+u <= i) mloc = fmaxf(mloc, raw[u]);
    }
    float m1 = waveAllMax(mloc);
    float e[4], c[4]; float lsum = 0.f;
    #pragma unroll
    for(int u=0;u<4;u++){
      e[u] = (j0+u <= i) ? __expf(raw[u]-m1) : 0.f;
      lsum += e[u]; c[u] = lsum;
    }
    float s = lsum;
    #pragma unroll
    for(int o=1;o<64;o<<=1){ float tv = __shfl_up(s,o,64); if(lane>=o) s += tv; }
    float pre = s - lsum;
    float tot = __shfl(s, 63, 64);
    float invtot = 1.f/tot;

    float s2v[4]; float m2loc = -3e38f;
    #pragma unroll
    for(int u=0;u<4;u++){
      int j = j0+u;
      float cum  = (pre + c[u]) * invtot;
      float remn = fmaxf(1.f - cum, 0.f);
      float dist = sqrtf(remn * fabsf((float)(j - i)));
      float eff  = fminf(fmaxf(__expf(-ga*dist), 1e-5f), 1e5f);
      s2v[u] = raw[u]*eff;
      if(j <= i) m2loc = fmaxf(m2loc, s2v[u]);
    }
    float m2 = waveAllMax(m2loc);
    float e2[4]; float zloc = 0.f;
    #pragma unroll
    for(int u=0;u<4;u++){
      e2[u] = (j0+u <= i) ? __expf(s2v[u]-m2) : 0.f;
      zloc += e2[u];
    }
    float Z = waveAllSum(zloc);
    float invZ = 1.f/Z;
    float p0=e2[0]*invZ, p1=e2[1]*invZ, p2=e2[2]*invZ, p3=e2[3]*invZ;

    *(float4*)(qs + ((size_t)(bh*256 + i))*256 + j0) = make_float4(p0,p1,p2,p3);

    // wave-local LDS transpose (no barrier: psW[w] is wave-private, DS in-order)
    *(float4*)myChunk = make_float4(p0,p1,p2,p3);
    float4 acc = make_float4(0,0,0,0);
    #pragma unroll
    for(int k=0;k<4;k++){
      float4 pk = *(const float4*)(pw + 4*k);
      acc = f4fma(acc, pk.x, vreg[4*k  ]);
      acc = f4fma(acc, pk.y, vreg[4*k+1]);
      acc = f4fma(acc, pk.z, vreg[4*k+2]);
      acc = f4fma(acc, pk.w, vreg[4*k+3]);
    }
    #pragma unroll
    for(int o=4;o<64;o<<=1){
      acc.x += __shfl_xor(acc.x,o,64); acc.y += __shfl_xor(acc.y,o,64);
      acc.z += __shfl_xor(acc.z,o,64); acc.w += __shfl_xor(acc.w,o,64);
    }
    if(lane < 4)
      *(float4*)(aout + (b*256 + i)*128 + h*16 + lane*4) = acc;
  }
}

DEV float dot16(const float* a, const float* b){
  float s = 0.f;
  #pragma unroll
  for(int k=0;k<16;k++) s += a[k]*b[k];
  return s;
}

// ---------- Layer-4 main: fused scan, (d4,jg) PV partition ----------
// grid: 2048 = 512 bnh * 4 quarters; block 256 = 4 waves; 16 rows/wave
__global__ __launch_bounds__(256) void attn4_main(
  const float* __restrict__ q4, const float* __restrict__ k4,
  const float* __restrict__ v4, const float* __restrict__ gamma,
  float* __restrict__ ks, float* __restrict__ aout)
{
  __shared__ float sc4[4];
  __shared__ float rawL[256];
  __shared__ float PL[256];
  __shared__ float psW[4][320];   // wave-private, 16 chunks * 20 floats
  int quarter = blockIdx.x & 3;
  int bnh  = blockIdx.x >> 2;
  int b = bnh >> 7, n = (bnh >> 3) & 15, h = bnh & 7;
  int t = threadIdx.x, lane = t & 63, w = t >> 6;
  int d4 = lane & 3, jg = lane >> 2;
  int j0 = 4*lane;

  // fused attn4_pre: raw[j] and prefix P[j] of exp(raw - M), in LDS
  {
    const float* qrow = q4 + n*128 + h*16;
    const float* krow = k4 + (b*256 + t)*128 + h*16;
    float raw = dot16(qrow, krow) * 0.25f;
    float M = blockMax256(raw, sc4);
    float E = __expf(raw - M);
    float tot;
    float P = blockScan256(E, sc4, tot);
    rawL[t] = raw;
    PL[t]   = P;
  }
  // V panel: lane (d4,jg) holds V[jg*16+jj][4d4..4d4+3]
  float4 vreg[16];
  #pragma unroll
  for(int jj=0;jj<16;jj++)
    vreg[jj] = *(const float4*)(v4 + (b*256 + jg*16 + jj)*128 + h*16 + d4*4);
  __syncthreads();   // rawL/PL visible to all waves (once)

  float4 rw = *(const float4*)(rawL + j0);
  float4 Pv = *(const float4*)(PL + j0);
  float P_[4] = {Pv.x, Pv.y, Pv.z, Pv.w};
  float R_[4] = {rw.x, rw.y, rw.z, rw.w};

  float g4a = fabsf(gamma[h]);
  size_t ksrowbase = ((size_t)(b*8 + h)*256)*4096 + (size_t)n*256 + j0;
  float* myChunk = &psW[w][(lane>>2)*20 + 4*(lane&3)];
  const float* pw = &psW[w][jg*20];

  for(int r=0;r<16;r++){
    int i = quarter*64 + w*16 + r;   // wave-uniform
    float p0=0.f,p1=0.f,p2=0.f,p3=0.f;
    if(i > 0){
      float invPm1 = 1.f / PL[i-1];  // LDS broadcast (read-only region now)
      float s2v[4]; float mloc = -3e38f;
      #pragma unroll
      for(int u=0;u<4;u++){
        int j = j0+u;
        float cum  = P_[u]*invPm1;
        float remn = fmaxf(1.f - cum, 0.f);
        float dist = sqrtf(remn * fabsf((float)(j - i)));
        float eff  = fminf(fmaxf(__expf(-g4a*dist), 1e-5f), 1e5f);
        float s2   = R_[u]*eff;
        s2v[u] = s2;
        if(j < i) mloc = fmaxf(mloc, s2);
      }
      float m2 = waveAllMax(mloc);
      float e_[4]; float zloc = 0.f;
      #pragma unroll
      for(int u=0;u<4;u++){
        float e = (j0+u < i) ? __expf(s2v[u]-m2) : 0.f;
        e_[u] = e; zloc += e;
      }
      float Z = waveAllSum(zloc);
      float sc = fminf(5.f/Z, 1.f);  // maxout: max(p)=1/Z -> scale=min(Z,5)/Z
      p0=e_[0]*sc; p1=e_[1]*sc; p2=e_[2]*sc; p3=e_[3]*sc;
    }
    *(float4*)(ks + ksrowbase + (size_t)i*4096) = make_float4(p0,p1,p2,p3);

    // wave-local LDS transpose (no barrier)
    *(float4*)myChunk = make_float4(p0,p1,p2,p3);
    float4 acc = make_float4(0,0,0,0);
    #pragma unroll
    for(int k=0;k<4;k++){
      float4 pk = *(const float4*)(pw + 4*k);
      acc = f4fma(acc, pk.x, vreg[4*k  ]);
      acc = f4fma(acc, pk.y, vreg[4*k+1]);
      acc = f4fma(acc, pk.z, vreg[4*k+2]);
      acc = f4fma(acc, pk.w, vreg[4*k+3]);
    }
    #pragma unroll
    for(int o=4;o<64;o<<=1){
      acc.x += __shfl_xor(acc.x,o,64); acc.y += __shfl_xor(acc.y,o,64);
      acc.z += __shfl_xor(acc.z,o,64); acc.w += __shfl_xor(acc.w,o,64);
    }
    if(lane < 4)
      *(float4*)(aout + ((b*16+n)*256 + i)*128 + h*16 + lane*4) = acc;
  }
}

extern "C" void kernel_launch(void* const* d_in, const int* in_sizes, int n_in,
                              void* d_out, int out_size, void* d_ws, size_t ws_size,
                              hipStream_t stream)
{
  (void)in_sizes; (void)n_in; (void)out_size; (void)ws_size;
  const float* q_emb   = (const float*)d_in[0];
  const float* s_emb   = (const float*)d_in[1];
  const float* b1_Wq   = (const float*)d_in[3];
  const float* b1_bq   = (const float*)d_in[4];
  const float* b1_Wv   = (const float*)d_in[5];
  const float* b1_bv   = (const float*)d_in[6];
  const float* b1_Wo   = (const float*)d_in[7];
  const float* b1_bo   = (const float*)d_in[8];
  const float* b1_gamma= (const float*)d_in[9];
  const float* b1_lng  = (const float*)d_in[10];
  const float* b1_lnb  = (const float*)d_in[11];
  const float* b4_Wq   = (const float*)d_in[12];
  const float* b4_bq   = (const float*)d_in[13];
  const float* b4_Wk   = (const float*)d_in[14];
  const float* b4_bk   = (const float*)d_in[15];
  const float* b4_Wv   = (const float*)d_in[16];
  const float* b4_bv   = (const float*)d_in[17];
  const float* b4_Wo   = (const float*)d_in[18];
  const float* b4_bo   = (const float*)d_in[19];
  const float* b4_gamma= (const float*)d_in[20];
  const float* b4_lng  = (const float*)d_in[21];
  const float* b4_lnb  = (const float*)d_in[22];
  const float* know    = (const float*)d_in[23];

  float* w    = (float*)d_ws;
  float* qk1  = w;                 // 131072
  float* v1   = w + 131072;        // 131072
  float* a1o  = w + 262144;        // 131072
  float* p    = w + 393216;        // 131072
  float* q4   = w + 524288;        // 2048
  float* k4   = w + 526336;        // 131072
  float* v4   = w + 657408;        // 131072
  float* a4o  = w + 788480;        // 2097152

  float* z_out  = (float*)d_out;                 // (4,256,2048)
  float* qs_out = z_out + 2097152;               // (4,8,256,256)
  float* ks_out = z_out + 4194304;               // (4,8,256,16,256)

  // L1: fused projections qk1, v1, k4, q4
  proj4_kernel<<<193,256,0,stream>>>(
      q_emb, b1_Wq, b1_bq, qk1,
      s_emb, b1_Wv, b1_bv, v1,
      q_emb, b4_Wk, b4_bk, k4,
      know,  b4_Wq, b4_bq, q4);

  // L2: layer-1 attention
  attn1_kernel<<<512,256,0,stream>>>(qk1, v1, b1_gamma, qs_out, a1o);

  // L3: p = LN(a1o@Wo+bo+q_emb); v4 = p@Wv+bv   (fused)
  gemm_p_v4<<<64,256,0,stream>>>(a1o, b1_Wo, b1_bo, q_emb, b1_lng, b1_lnb, p,
                                 b4_Wv, b4_bv, v4);

  // L4: layer-4 attention (scan fused in)
  attn4_main<<<2048,256,0,stream>>>(q4, k4, v4, b4_gamma, ks_out, a4o);

  // L5: z projection + LN
  gemm16_kernel<2><<<1024,256,0,stream>>>(a4o, b4_Wo, b4_bo, know, b4_lng, b4_lnb, z_out, 16384);
}